// Round 6
// baseline (551.844 us; speedup 1.0000x reference)
//
#include <hip/hip_runtime.h>
#include <hip/hip_bf16.h>

#define N_NODES 100000
#define N_EDGES 1600000
#define IN_DIM 128
#define HID 256
#define NUM_GRAPHS 2048
#define M_PAD 100096  // 782 * 128
#define SCAN_BLOCKS 98  // ceil(100000/1024)

typedef __bf16 bf16x8 __attribute__((ext_vector_type(8)));
typedef float f32x4 __attribute__((ext_vector_type(4)));

__device__ inline unsigned short f2bf(float x) {
    union { __hip_bfloat16 h; unsigned short u; } v;
    v.h = __float2bfloat16(x);
    return v.u;
}
__device__ inline float bf2f(unsigned short u) {
    return __uint_as_float(((unsigned int)u) << 16);
}
__device__ inline int rfl(int x) { return __builtin_amdgcn_readfirstlane(x); }

// ---------------- degree histogram over dst + per-edge ordinal ----------------
__global__ void count_deg_kernel(const int* __restrict__ ei, int* __restrict__ deg,
                                 int* __restrict__ eord) {
    int e = blockIdx.x * blockDim.x + threadIdx.x;
    if (e < N_EDGES) {
        eord[e] = atomicAdd(&deg[ei[N_EDGES + e]], 1);
    }
}

// ---------------- block sums (+ fused dinv) ----------------
__global__ __launch_bounds__(1024) void blocksum_kernel(const int* __restrict__ deg,
                                                        int* __restrict__ bsum,
                                                        float* __restrict__ dinv) {
    int i = blockIdx.x * 1024 + threadIdx.x;
    int v = (i < N_NODES) ? deg[i] : 0;
    if (i < N_NODES) dinv[i] = rsqrtf((float)(v + 1));  // self-loop adds 1
    __shared__ int s[1024];
    int t = threadIdx.x;
    s[t] = v;
    __syncthreads();
#pragma unroll
    for (int off = 512; off > 0; off >>= 1) {
        if (t < off) s[t] += s[t + off];
        __syncthreads();
    }
    if (t == 0) bsum[blockIdx.x] = s[0];
}

__global__ __launch_bounds__(128) void bscan_kernel(int* __restrict__ bsum) {
    __shared__ int s[128];
    int t = threadIdx.x;
    int v = (t < SCAN_BLOCKS) ? bsum[t] : 0;
    s[t] = v;
    __syncthreads();
#pragma unroll
    for (int off = 1; off < 128; off <<= 1) {
        int x = (t >= off) ? s[t - off] : 0;
        __syncthreads();
        s[t] += x;
        __syncthreads();
    }
    if (t < SCAN_BLOCKS) bsum[t] = (t > 0) ? s[t - 1] : 0;  // exclusive
}

__global__ __launch_bounds__(1024) void scanout_kernel(const int* __restrict__ deg,
                                                       const int* __restrict__ bsum,
                                                       int* __restrict__ rowptr) {
    int i = blockIdx.x * 1024 + threadIdx.x;
    int t = threadIdx.x;
    int v = (i < N_NODES) ? deg[i] : 0;
    __shared__ int s[1024];
    s[t] = v;
    __syncthreads();
#pragma unroll
    for (int off = 1; off < 1024; off <<= 1) {
        int x = (t >= off) ? s[t - off] : 0;
        __syncthreads();
        s[t] += x;
        __syncthreads();
    }
    int base = bsum[blockIdx.x];
    int excl = (t > 0) ? s[t - 1] : 0;
    if (i < N_NODES) rowptr[i] = base + excl;
    if (i == N_NODES - 1) rowptr[N_NODES] = base + s[t];
}

// ---------------- bucket fill: CSR src list sorted by dst (atomic-free) ----------
__global__ void fill_kernel(const int* __restrict__ ei, const int* __restrict__ rowptr,
                            const int* __restrict__ eord, int* __restrict__ esrc) {
    int e = blockIdx.x * blockDim.x + threadIdx.x;
    if (e < N_EDGES) {
        int dst = ei[N_EDGES + e];
        esrc[rowptr[dst] + eord[e]] = ei[e];
    }
}

// ---------------- x -> bf16, prescaled by dinv[row] ----------------
// X' = bf16(dinv[row] * x): folds the per-edge dinv[src] factor into the
// gather table so agg kernels do pure adds (no per-edge dinv gather/mul).
__global__ void x2bf_kernel(const float* __restrict__ x, const float* __restrict__ dinv,
                            unsigned short* __restrict__ xb) {
    size_t i = ((size_t)blockIdx.x * 256 + threadIdx.x) * 4;
    int node = (int)(i >> 7);  // 128 floats per row
    float dv = dinv[node];
    float4 v = *(const float4*)(x + i);
    ushort4 o;
    o.x = f2bf(v.x * dv); o.y = f2bf(v.y * dv);
    o.z = f2bf(v.z * dv); o.w = f2bf(v.w * dv);
    *(ushort4*)(xb + i) = o;
}

// ---------------- both weight transposes + bf16 splits in one launch ----------
__global__ void wsplit_all_kernel(const float* __restrict__ W1, const float* __restrict__ W2,
                                  unsigned short* __restrict__ W1th, unsigned short* __restrict__ W1tl,
                                  unsigned short* __restrict__ W2th, unsigned short* __restrict__ W2tl) {
    int idx = blockIdx.x * 256 + threadIdx.x;
    if (idx < IN_DIM * 256) {
        int k = idx >> 8, n = idx & 255;
        float w = W1[idx];
        unsigned short h = f2bf(w);
        unsigned short l = f2bf(w - bf2f(h));
        W1th[n * IN_DIM + k] = h;
        W1tl[n * IN_DIM + k] = l;
    } else {
        int i2 = idx - IN_DIM * 256;
        int k = i2 >> 8, n = i2 & 255;
        float w = W2[i2];
        unsigned short h = f2bf(w);
        unsigned short l = f2bf(w - bf2f(h));
        W2th[n * HID + k] = h;
        W2tl[n * HID + k] = l;
    }
}

// ---------------- gather agg 128-dim from prescaled bf16, hi/lo out ----------
// A[dst] = ddst * ( X'[dst] + sum_src X'[src] ); X' already carries dinv[src].
__global__ __launch_bounds__(256) void agg128_kernel(const unsigned short* __restrict__ X,
                                                     const int* __restrict__ esrc,
                                                     const int* __restrict__ rowptr,
                                                     const float* __restrict__ dinv,
                                                     unsigned short* __restrict__ Ah,
                                                     unsigned short* __restrict__ Al) {
    int node = rfl(blockIdx.x * 4 + (threadIdx.x >> 6));
    int lane = threadIdx.x & 63;
    float ddst = dinv[node];
    int s = rfl(rowptr[node]);
    int e = rfl(rowptr[node + 1]);

    ushort2 h0 = *((const ushort2*)(X + (size_t)node * 128) + lane);
    float2 acc = make_float2(bf2f(h0.x), bf2f(h0.y));

    int j = s;
    for (; j + 8 <= e; j += 8) {
        int si[8];
#pragma unroll
        for (int u = 0; u < 8; u++) si[u] = rfl(esrc[j + u]);
        ushort2 xv[8];
#pragma unroll
        for (int u = 0; u < 8; u++)
            xv[u] = *((const ushort2*)(X + (size_t)si[u] * 128) + lane);
#pragma unroll
        for (int u = 0; u < 8; u++) {
            acc.x += bf2f(xv[u].x);
            acc.y += bf2f(xv[u].y);
        }
    }
    for (; j + 4 <= e; j += 4) {
        int si[4];
#pragma unroll
        for (int u = 0; u < 4; u++) si[u] = rfl(esrc[j + u]);
        ushort2 xv[4];
#pragma unroll
        for (int u = 0; u < 4; u++)
            xv[u] = *((const ushort2*)(X + (size_t)si[u] * 128) + lane);
#pragma unroll
        for (int u = 0; u < 4; u++) {
            acc.x += bf2f(xv[u].x);
            acc.y += bf2f(xv[u].y);
        }
    }
    for (; j < e; j++) {
        int src = rfl(esrc[j]);
        ushort2 xv = *((const ushort2*)(X + (size_t)src * 128) + lane);
        acc.x += bf2f(xv.x);
        acc.y += bf2f(xv.y);
    }
    acc.x *= ddst;
    acc.y *= ddst;
    size_t o = (size_t)node * 128 + lane * 2;
    unsigned short hx = f2bf(acc.x), hy = f2bf(acc.y);
    unsigned short lx = f2bf(acc.x - bf2f(hx)), ly = f2bf(acc.y - bf2f(hy));
    // non-temporal: streaming output, keep L2/L3 for the gather table
    __builtin_nontemporal_store((unsigned int)hx | ((unsigned int)hy << 16),
                                (unsigned int*)(Ah + o));
    __builtin_nontemporal_store((unsigned int)lx | ((unsigned int)ly << 16),
                                (unsigned int*)(Al + o));
}

// ---------------- gather agg 256-dim from prescaled bf16, hi out ----------
__global__ __launch_bounds__(256) void agg256_kernel(const unsigned short* __restrict__ H,
                                                     const int* __restrict__ esrc,
                                                     const int* __restrict__ rowptr,
                                                     const float* __restrict__ dinv,
                                                     unsigned short* __restrict__ Ah) {
    int node = rfl(blockIdx.x * 4 + (threadIdx.x >> 6));
    int lane = threadIdx.x & 63;
    float ddst = dinv[node];
    int s = rfl(rowptr[node]);
    int e = rfl(rowptr[node + 1]);

    ushort4 h0 = *((const ushort4*)(H + (size_t)node * 256) + lane);
    float4 acc = make_float4(bf2f(h0.x), bf2f(h0.y), bf2f(h0.z), bf2f(h0.w));

    int j = s;
    for (; j + 8 <= e; j += 8) {
        int si[8];
#pragma unroll
        for (int u = 0; u < 8; u++) si[u] = rfl(esrc[j + u]);
        ushort4 xv[8];
#pragma unroll
        for (int u = 0; u < 8; u++)
            xv[u] = *((const ushort4*)(H + (size_t)si[u] * 256) + lane);
#pragma unroll
        for (int u = 0; u < 8; u++) {
            acc.x += bf2f(xv[u].x);
            acc.y += bf2f(xv[u].y);
            acc.z += bf2f(xv[u].z);
            acc.w += bf2f(xv[u].w);
        }
    }
    for (; j + 4 <= e; j += 4) {
        int si[4];
#pragma unroll
        for (int u = 0; u < 4; u++) si[u] = rfl(esrc[j + u]);
        ushort4 xv[4];
#pragma unroll
        for (int u = 0; u < 4; u++)
            xv[u] = *((const ushort4*)(H + (size_t)si[u] * 256) + lane);
#pragma unroll
        for (int u = 0; u < 4; u++) {
            acc.x += bf2f(xv[u].x);
            acc.y += bf2f(xv[u].y);
            acc.z += bf2f(xv[u].z);
            acc.w += bf2f(xv[u].w);
        }
    }
    for (; j < e; j++) {
        int src = rfl(esrc[j]);
        ushort4 xv = *((const ushort4*)(H + (size_t)src * 256) + lane);
        acc.x += bf2f(xv.x);
        acc.y += bf2f(xv.y);
        acc.z += bf2f(xv.z);
        acc.w += bf2f(xv.w);
    }
    acc.x *= ddst; acc.y *= ddst; acc.z *= ddst; acc.w *= ddst;
    size_t o = (size_t)node * 256 + lane * 4;
    unsigned long long v =
        (unsigned long long)f2bf(acc.x) |
        ((unsigned long long)f2bf(acc.y) << 16) |
        ((unsigned long long)f2bf(acc.z) << 32) |
        ((unsigned long long)f2bf(acc.w) << 48);
    __builtin_nontemporal_store(v, (unsigned long long*)(Ah + o));
}

// ---------------- MFMA GEMM: C = relu(A @ W + b) [optionally * dinv[row]] ------
// ASPLIT: A has hi+lo (3-term product) else hi only (2-term). Output bf16.
// SCALEOUT: multiply output row by dscale[row] (prescale for next gather).
template <int K, bool ASPLIT, bool SCALEOUT>
__launch_bounds__(256, 2)
__global__ void mfma_gemm_bias_relu(const unsigned short* __restrict__ Ah,
                                    const unsigned short* __restrict__ Al,
                                    const unsigned short* __restrict__ Bh,
                                    const unsigned short* __restrict__ Bl,
                                    const float* __restrict__ bias,
                                    const float* __restrict__ dscale,
                                    unsigned short* __restrict__ Cout) {
    constexpr int NT = ASPLIT ? 4 : 3;
    __shared__ __align__(16) unsigned short lds[NT * 128 * 32];
    unsigned short* Ahs = lds;
    unsigned short* Als = lds + 4096;                    // only valid if ASPLIT
    unsigned short* Bhs = lds + (ASPLIT ? 8192 : 4096);
    unsigned short* Bls = lds + (ASPLIT ? 12288 : 8192);

    int tid = threadIdx.x;
    int bm = blockIdx.x * 128;
    int bn = blockIdx.y * 128;
    int wid = tid >> 6, lane = tid & 63;
    int wm = wid & 1, wn = wid >> 1;
    int lrow = lane & 15, quad = lane >> 4;

    f32x4 acc[4][4];
#pragma unroll
    for (int mi = 0; mi < 4; mi++)
#pragma unroll
        for (int ni = 0; ni < 4; ni++) acc[mi][ni] = (f32x4){0.f, 0.f, 0.f, 0.f};

    for (int k0 = 0; k0 < K; k0 += 32) {
#pragma unroll
        for (int i = 0; i < NT * 2; i++) {
            int c = tid + 256 * i;
            int tile = c >> 9;
            int w = c & 511;
            int row = w >> 2;
            int part = w & 3;
            const unsigned short* g;
            if (ASPLIT) {
                if (tile == 0)      g = Ah + (size_t)(bm + row) * K + k0 + part * 8;
                else if (tile == 1) g = Al + (size_t)(bm + row) * K + k0 + part * 8;
                else if (tile == 2) g = Bh + (size_t)(bn + row) * K + k0 + part * 8;
                else                g = Bl + (size_t)(bn + row) * K + k0 + part * 8;
            } else {
                if (tile == 0)      g = Ah + (size_t)(bm + row) * K + k0 + part * 8;
                else if (tile == 1) g = Bh + (size_t)(bn + row) * K + k0 + part * 8;
                else                g = Bl + (size_t)(bn + row) * K + k0 + part * 8;
            }
            ulonglong2 v = *(const ulonglong2*)g;
            *(ulonglong2*)&lds[(tile << 12) + row * 32 + part * 8] = v;
        }
        __syncthreads();

        bf16x8 ah[4], al[4], bh[4], bl[4];
#pragma unroll
        for (int mi = 0; mi < 4; mi++) {
            int r = wm * 64 + mi * 16 + lrow;
            ah[mi] = *(const bf16x8*)&Ahs[r * 32 + quad * 8];
            if (ASPLIT) al[mi] = *(const bf16x8*)&Als[r * 32 + quad * 8];
        }
#pragma unroll
        for (int ni = 0; ni < 4; ni++) {
            int r = wn * 64 + ni * 16 + lrow;
            bh[ni] = *(const bf16x8*)&Bhs[r * 32 + quad * 8];
            bl[ni] = *(const bf16x8*)&Bls[r * 32 + quad * 8];
        }
#pragma unroll
        for (int mi = 0; mi < 4; mi++)
#pragma unroll
            for (int ni = 0; ni < 4; ni++) {
                acc[mi][ni] = __builtin_amdgcn_mfma_f32_16x16x32_bf16(ah[mi], bh[ni], acc[mi][ni], 0, 0, 0);
                acc[mi][ni] = __builtin_amdgcn_mfma_f32_16x16x32_bf16(ah[mi], bl[ni], acc[mi][ni], 0, 0, 0);
                if (ASPLIT)
                    acc[mi][ni] = __builtin_amdgcn_mfma_f32_16x16x32_bf16(al[mi], bh[ni], acc[mi][ni], 0, 0, 0);
            }
        __syncthreads();
    }

    float bv[4];
#pragma unroll
    for (int ni = 0; ni < 4; ni++) bv[ni] = bias[bn + wn * 64 + ni * 16 + lrow];
#pragma unroll
    for (int mi = 0; mi < 4; mi++) {
        int row0 = bm + wm * 64 + mi * 16 + quad * 4;
        float dsc[4];
        if (SCALEOUT) {
#pragma unroll
            for (int r = 0; r < 4; r++)
                dsc[r] = (row0 + r < N_NODES) ? dscale[row0 + r] : 0.f;
        }
#pragma unroll
        for (int ni = 0; ni < 4; ni++) {
            int col = bn + wn * 64 + ni * 16 + lrow;
#pragma unroll
            for (int r = 0; r < 4; r++) {
                int row = row0 + r;
                if (row < N_NODES) {
                    float v = fmaxf(acc[mi][ni][r] + bv[ni], 0.f);
                    if (SCALEOUT) v *= dsc[r];
                    Cout[(size_t)row * 256 + col] = f2bf(v);
                }
            }
        }
    }
}

// ---------------- fused mean-pool (batch sorted, h in bf16) + MLP head ----------
__global__ __launch_bounds__(256) void pool_mlp_kernel(const unsigned short* __restrict__ h,
                                                       const int* __restrict__ batch,
                                                       const float* __restrict__ Wf1,
                                                       const float* __restrict__ bf1,
                                                       const float* __restrict__ Wf2,
                                                       const float* __restrict__ bf2,
                                                       float* __restrict__ out) {
    int g = blockIdx.x;
    int t = threadIdx.x;  // 0..255
    __shared__ int bounds[2];
    if (t < 2) {
        int target = g + t;
        int lo = 0, hi = N_NODES;
        while (lo < hi) {
            int mid = (lo + hi) >> 1;
            if (batch[mid] < target) lo = mid + 1;
            else hi = mid;
        }
        bounds[t] = lo;
    }
    __syncthreads();
    int lo = bounds[0], hi = bounds[1];

    float acc = 0.f;
    for (int n = lo; n < hi; n++) acc += bf2f(h[(size_t)n * HID + t]);
    float inv = (hi > lo) ? 1.0f / (float)(hi - lo) : 0.f;
    __shared__ float p[256];
    p[t] = acc * inv;
    __syncthreads();

    float hv = 0.f;
    if (t < 128) {
        float a = bf1[t];
#pragma unroll 8
        for (int k = 0; k < 256; k++) a = fmaf(p[k], Wf1[k * 128 + t], a);
        hv = fmaxf(a, 0.f) * Wf2[t];
    }
#pragma unroll
    for (int off = 32; off > 0; off >>= 1) hv += __shfl_down(hv, off, 64);
    __shared__ float partial[4];
    if ((t & 63) == 0) partial[t >> 6] = hv;
    __syncthreads();
    if (t == 0) out[g] = partial[0] + partial[1] + bf2[0];
}

extern "C" void kernel_launch(void* const* d_in, const int* in_sizes, int n_in,
                              void* d_out, int out_size, void* d_ws, size_t ws_size,
                              hipStream_t stream) {
    const float* x   = (const float*)d_in[0];
    const int*   ei  = (const int*)d_in[1];
    const int*   bat = (const int*)d_in[2];
    const float* W1  = (const float*)d_in[3];
    const float* b1  = (const float*)d_in[4];
    const float* W2  = (const float*)d_in[5];
    const float* b2  = (const float*)d_in[6];
    const float* Wf1 = (const float*)d_in[7];
    const float* bf1 = (const float*)d_in[8];
    const float* Wf2 = (const float*)d_in[9];
    const float* bf2 = (const float*)d_in[10];
    float* out = (float*)d_out;

    char* ws = (char*)d_ws;
    // layout (peak end 0x9B20000 = 162.5 MB):
    //   0x0000000 deg        0x0080000 dinv      0x0100000 rowptr
    //   0x01F0000 bsum
    //   0x0200000 esrc (6.4 MB)
    //   0x0820000 W1th  0x0830000 W1tl  0x0840000 W2th  0x0860000 W2tl
    //   0x0880000 A1h (25.6 MB) / later A2 (51.2 MB, single)
    //   0x20F0000 eord (6.4 MB, dead after fill) -> A1l (25.6 MB)  [A2 overlaps]
    //   0x6A40000 xbf (25.6 MB) -> H1bf (51.2 MB) -> H2bf (51.2 MB) time-multiplexed
    int*   deg    = (int*)(ws);
    float* dinv   = (float*)(ws + 0x0080000);
    int*   rowptr = (int*)(ws + 0x0100000);
    int*   bsum   = (int*)(ws + 0x01F0000);
    int*   esrc   = (int*)(ws + 0x0200000);
    unsigned short* W1th = (unsigned short*)(ws + 0x0820000);
    unsigned short* W1tl = (unsigned short*)(ws + 0x0830000);
    unsigned short* W2th = (unsigned short*)(ws + 0x0840000);
    unsigned short* W2tl = (unsigned short*)(ws + 0x0860000);
    unsigned short* A1h  = (unsigned short*)(ws + 0x0880000);
    int*   eord   = (int*)(ws + 0x20F0000);                    // dead before A1l written
    unsigned short* A1l  = (unsigned short*)(ws + 0x20F0000);
    unsigned short* A2   = (unsigned short*)(ws + 0x0880000);  // reuses A1h+A1l space
    unsigned short* xbf  = (unsigned short*)(ws + 0x6A40000);
    unsigned short* H1bf = (unsigned short*)(ws + 0x6A40000);  // overwrites dead xbf
    unsigned short* H2bf = (unsigned short*)(ws + 0x6A40000);  // overwrites dead H1bf
    (void)ws_size;

    hipMemsetAsync(deg, 0, (size_t)N_NODES * sizeof(int), stream);

    // CSR build front half (produces dinv needed by the prescaled x2bf)
    count_deg_kernel<<<(N_EDGES + 255) / 256, 256, 0, stream>>>(ei, deg, eord);
    blocksum_kernel<<<SCAN_BLOCKS, 1024, 0, stream>>>(deg, bsum, dinv);

    // prep (x2bf now consumes dinv for the prescale)
    x2bf_kernel<<<(N_NODES * IN_DIM / 4) / 256, 256, 0, stream>>>(x, dinv, xbf);
    wsplit_all_kernel<<<((IN_DIM + HID) * 256) / 256, 256, 0, stream>>>(W1, W2, W1th, W1tl, W2th, W2tl);

    // CSR build back half
    bscan_kernel<<<1, 128, 0, stream>>>(bsum);
    scanout_kernel<<<SCAN_BLOCKS, 1024, 0, stream>>>(deg, bsum, rowptr);
    fill_kernel<<<(N_EDGES + 255) / 256, 256, 0, stream>>>(ei, rowptr, eord, esrc);

    // layer 1: A1 = split(ddst * sum X'); H1' = dinv * relu(A1 @ W1 + b1)  [3-term]
    agg128_kernel<<<N_NODES / 4, 256, 0, stream>>>(xbf, esrc, rowptr, dinv, A1h, A1l);
    {
        dim3 grid(M_PAD / 128, 2);
        mfma_gemm_bias_relu<IN_DIM, true, true><<<grid, 256, 0, stream>>>(A1h, A1l, W1th, W1tl, b1, dinv, H1bf);
    }

    // layer 2: A2 = bf16(ddst * sum H1'); H2 = relu(A2 @ W2 + b2)  [2-term]
    agg256_kernel<<<N_NODES / 4, 256, 0, stream>>>(H1bf, esrc, rowptr, dinv, A2);
    {
        dim3 grid(M_PAD / 128, 2);
        mfma_gemm_bias_relu<HID, false, false><<<grid, 256, 0, stream>>>(A2, nullptr, W2th, W2tl, b2, nullptr, H2bf);
    }

    // pooling + MLP head (bf16 h)
    pool_mlp_kernel<<<NUM_GRAPHS, 256, 0, stream>>>(H2bf, bat, Wf1, bf1, Wf2, bf2, out);
}

// Round 7
// 546.737 us; speedup vs baseline: 1.0093x; 1.0093x over previous
//
#include <hip/hip_runtime.h>
#include <hip/hip_bf16.h>

#define N_NODES 100000
#define N_EDGES 1600000
#define IN_DIM 128
#define HID 256
#define NUM_GRAPHS 2048
#define M_PAD 100096  // 782 * 128
#define SCAN_BLOCKS 98  // ceil(100000/1024)

typedef __bf16 bf16x8 __attribute__((ext_vector_type(8)));
typedef float f32x4 __attribute__((ext_vector_type(4)));

__device__ inline unsigned short f2bf(float x) {
    union { __hip_bfloat16 h; unsigned short u; } v;
    v.h = __float2bfloat16(x);
    return v.u;
}
__device__ inline float bf2f(unsigned short u) {
    return __uint_as_float(((unsigned int)u) << 16);
}
__device__ inline int rfl(int x) { return __builtin_amdgcn_readfirstlane(x); }

// ---------------- degree histogram over dst + per-edge ordinal ----------------
__global__ void count_deg_kernel(const int* __restrict__ ei, int* __restrict__ deg,
                                 int* __restrict__ eord) {
    int e = blockIdx.x * blockDim.x + threadIdx.x;
    if (e < N_EDGES) {
        eord[e] = atomicAdd(&deg[ei[N_EDGES + e]], 1);
    }
}

// ---------------- block sums (+ fused dinv) ----------------
__global__ __launch_bounds__(1024) void blocksum_kernel(const int* __restrict__ deg,
                                                        int* __restrict__ bsum,
                                                        float* __restrict__ dinv) {
    int i = blockIdx.x * 1024 + threadIdx.x;
    int v = (i < N_NODES) ? deg[i] : 0;
    if (i < N_NODES) dinv[i] = rsqrtf((float)(v + 1));  // self-loop adds 1
    __shared__ int s[1024];
    int t = threadIdx.x;
    s[t] = v;
    __syncthreads();
#pragma unroll
    for (int off = 512; off > 0; off >>= 1) {
        if (t < off) s[t] += s[t + off];
        __syncthreads();
    }
    if (t == 0) bsum[blockIdx.x] = s[0];
}

__global__ __launch_bounds__(128) void bscan_kernel(int* __restrict__ bsum) {
    __shared__ int s[128];
    int t = threadIdx.x;
    int v = (t < SCAN_BLOCKS) ? bsum[t] : 0;
    s[t] = v;
    __syncthreads();
#pragma unroll
    for (int off = 1; off < 128; off <<= 1) {
        int x = (t >= off) ? s[t - off] : 0;
        __syncthreads();
        s[t] += x;
        __syncthreads();
    }
    if (t < SCAN_BLOCKS) bsum[t] = (t > 0) ? s[t - 1] : 0;  // exclusive
}

__global__ __launch_bounds__(1024) void scanout_kernel(const int* __restrict__ deg,
                                                       const int* __restrict__ bsum,
                                                       int* __restrict__ rowptr) {
    int i = blockIdx.x * 1024 + threadIdx.x;
    int t = threadIdx.x;
    int v = (i < N_NODES) ? deg[i] : 0;
    __shared__ int s[1024];
    s[t] = v;
    __syncthreads();
#pragma unroll
    for (int off = 1; off < 1024; off <<= 1) {
        int x = (t >= off) ? s[t - off] : 0;
        __syncthreads();
        s[t] += x;
        __syncthreads();
    }
    int base = bsum[blockIdx.x];
    int excl = (t > 0) ? s[t - 1] : 0;
    if (i < N_NODES) rowptr[i] = base + excl;
    if (i == N_NODES - 1) rowptr[N_NODES] = base + s[t];
}

// ---------------- bucket fill: CSR src list sorted by dst (atomic-free) ----------
__global__ void fill_kernel(const int* __restrict__ ei, const int* __restrict__ rowptr,
                            const int* __restrict__ eord, int* __restrict__ esrc) {
    int e = blockIdx.x * blockDim.x + threadIdx.x;
    if (e < N_EDGES) {
        int dst = ei[N_EDGES + e];
        esrc[rowptr[dst] + eord[e]] = ei[e];
    }
}

// ---------------- x -> bf16, prescaled by dinv[row] ----------------
// X' = bf16(dinv[row] * x): folds the per-edge dinv[src] factor into the
// gather table so agg kernels do pure adds (no per-edge dinv gather/mul).
__global__ void x2bf_kernel(const float* __restrict__ x, const float* __restrict__ dinv,
                            unsigned short* __restrict__ xb) {
    size_t i = ((size_t)blockIdx.x * 256 + threadIdx.x) * 4;
    int node = (int)(i >> 7);  // 128 floats per row
    float dv = dinv[node];
    float4 v = *(const float4*)(x + i);
    ushort4 o;
    o.x = f2bf(v.x * dv); o.y = f2bf(v.y * dv);
    o.z = f2bf(v.z * dv); o.w = f2bf(v.w * dv);
    *(ushort4*)(xb + i) = o;
}

// ---------------- both weight transposes + bf16 splits in one launch ----------
__global__ void wsplit_all_kernel(const float* __restrict__ W1, const float* __restrict__ W2,
                                  unsigned short* __restrict__ W1th, unsigned short* __restrict__ W1tl,
                                  unsigned short* __restrict__ W2th, unsigned short* __restrict__ W2tl) {
    int idx = blockIdx.x * 256 + threadIdx.x;
    if (idx < IN_DIM * 256) {
        int k = idx >> 8, n = idx & 255;
        float w = W1[idx];
        unsigned short h = f2bf(w);
        unsigned short l = f2bf(w - bf2f(h));
        W1th[n * IN_DIM + k] = h;
        W1tl[n * IN_DIM + k] = l;
    } else {
        int i2 = idx - IN_DIM * 256;
        int k = i2 >> 8, n = i2 & 255;
        float w = W2[i2];
        unsigned short h = f2bf(w);
        unsigned short l = f2bf(w - bf2f(h));
        W2th[n * HID + k] = h;
        W2tl[n * HID + k] = l;
    }
}

// ---------------- gather agg 128-dim from prescaled bf16, hi/lo out ----------
// A[dst] = ddst * ( X'[dst] + sum_src X'[src] ); X' already carries dinv[src].
// Plain stores (NOT non-temporal): A1 is re-read by GEMM1 within ~100us,
// keep it L3-resident (r6 post-mortem: NT stores cost ~+12us on the GEMMs).
__global__ __launch_bounds__(256) void agg128_kernel(const unsigned short* __restrict__ X,
                                                     const int* __restrict__ esrc,
                                                     const int* __restrict__ rowptr,
                                                     const float* __restrict__ dinv,
                                                     unsigned short* __restrict__ Ah,
                                                     unsigned short* __restrict__ Al) {
    int node = rfl(blockIdx.x * 4 + (threadIdx.x >> 6));
    int lane = threadIdx.x & 63;
    float ddst = dinv[node];
    int s = rfl(rowptr[node]);
    int e = rfl(rowptr[node + 1]);

    ushort2 h0 = *((const ushort2*)(X + (size_t)node * 128) + lane);
    float2 acc = make_float2(bf2f(h0.x), bf2f(h0.y));

    int j = s;
    for (; j + 8 <= e; j += 8) {
        int si[8];
#pragma unroll
        for (int u = 0; u < 8; u++) si[u] = rfl(esrc[j + u]);
        ushort2 xv[8];
#pragma unroll
        for (int u = 0; u < 8; u++)
            xv[u] = *((const ushort2*)(X + (size_t)si[u] * 128) + lane);
#pragma unroll
        for (int u = 0; u < 8; u++) {
            acc.x += bf2f(xv[u].x);
            acc.y += bf2f(xv[u].y);
        }
    }
    for (; j + 4 <= e; j += 4) {
        int si[4];
#pragma unroll
        for (int u = 0; u < 4; u++) si[u] = rfl(esrc[j + u]);
        ushort2 xv[4];
#pragma unroll
        for (int u = 0; u < 4; u++)
            xv[u] = *((const ushort2*)(X + (size_t)si[u] * 128) + lane);
#pragma unroll
        for (int u = 0; u < 4; u++) {
            acc.x += bf2f(xv[u].x);
            acc.y += bf2f(xv[u].y);
        }
    }
    for (; j < e; j++) {
        int src = rfl(esrc[j]);
        ushort2 xv = *((const ushort2*)(X + (size_t)src * 128) + lane);
        acc.x += bf2f(xv.x);
        acc.y += bf2f(xv.y);
    }
    acc.x *= ddst;
    acc.y *= ddst;
    size_t o = (size_t)node * 128 + lane * 2;
    ushort2 hi, lo;
    hi.x = f2bf(acc.x); lo.x = f2bf(acc.x - bf2f(hi.x));
    hi.y = f2bf(acc.y); lo.y = f2bf(acc.y - bf2f(hi.y));
    *(ushort2*)(Ah + o) = hi;
    *(ushort2*)(Al + o) = lo;
}

// ---------------- gather agg 256-dim from prescaled bf16, hi out ----------
__global__ __launch_bounds__(256) void agg256_kernel(const unsigned short* __restrict__ H,
                                                     const int* __restrict__ esrc,
                                                     const int* __restrict__ rowptr,
                                                     const float* __restrict__ dinv,
                                                     unsigned short* __restrict__ Ah) {
    int node = rfl(blockIdx.x * 4 + (threadIdx.x >> 6));
    int lane = threadIdx.x & 63;
    float ddst = dinv[node];
    int s = rfl(rowptr[node]);
    int e = rfl(rowptr[node + 1]);

    ushort4 h0 = *((const ushort4*)(H + (size_t)node * 256) + lane);
    float4 acc = make_float4(bf2f(h0.x), bf2f(h0.y), bf2f(h0.z), bf2f(h0.w));

    int j = s;
    for (; j + 8 <= e; j += 8) {
        int si[8];
#pragma unroll
        for (int u = 0; u < 8; u++) si[u] = rfl(esrc[j + u]);
        ushort4 xv[8];
#pragma unroll
        for (int u = 0; u < 8; u++)
            xv[u] = *((const ushort4*)(H + (size_t)si[u] * 256) + lane);
#pragma unroll
        for (int u = 0; u < 8; u++) {
            acc.x += bf2f(xv[u].x);
            acc.y += bf2f(xv[u].y);
            acc.z += bf2f(xv[u].z);
            acc.w += bf2f(xv[u].w);
        }
    }
    for (; j + 4 <= e; j += 4) {
        int si[4];
#pragma unroll
        for (int u = 0; u < 4; u++) si[u] = rfl(esrc[j + u]);
        ushort4 xv[4];
#pragma unroll
        for (int u = 0; u < 4; u++)
            xv[u] = *((const ushort4*)(H + (size_t)si[u] * 256) + lane);
#pragma unroll
        for (int u = 0; u < 4; u++) {
            acc.x += bf2f(xv[u].x);
            acc.y += bf2f(xv[u].y);
            acc.z += bf2f(xv[u].z);
            acc.w += bf2f(xv[u].w);
        }
    }
    for (; j < e; j++) {
        int src = rfl(esrc[j]);
        ushort4 xv = *((const ushort4*)(H + (size_t)src * 256) + lane);
        acc.x += bf2f(xv.x);
        acc.y += bf2f(xv.y);
        acc.z += bf2f(xv.z);
        acc.w += bf2f(xv.w);
    }
    acc.x *= ddst; acc.y *= ddst; acc.z *= ddst; acc.w *= ddst;
    size_t o = (size_t)node * 256 + lane * 4;
    ushort4 hi;
    hi.x = f2bf(acc.x); hi.y = f2bf(acc.y);
    hi.z = f2bf(acc.z); hi.w = f2bf(acc.w);
    *(ushort4*)(Ah + o) = hi;
}

// ---------------- MFMA GEMM: C = relu(A @ W + b) [optionally * dinv[row]] ------
// ASPLIT: A has hi+lo (3-term product) else hi only (2-term). Output bf16.
// SCALEOUT: multiply output row by dscale[row] (prescale for next gather).
template <int K, bool ASPLIT, bool SCALEOUT>
__launch_bounds__(256, 2)
__global__ void mfma_gemm_bias_relu(const unsigned short* __restrict__ Ah,
                                    const unsigned short* __restrict__ Al,
                                    const unsigned short* __restrict__ Bh,
                                    const unsigned short* __restrict__ Bl,
                                    const float* __restrict__ bias,
                                    const float* __restrict__ dscale,
                                    unsigned short* __restrict__ Cout) {
    constexpr int NT = ASPLIT ? 4 : 3;
    __shared__ __align__(16) unsigned short lds[NT * 128 * 32];
    unsigned short* Ahs = lds;
    unsigned short* Als = lds + 4096;                    // only valid if ASPLIT
    unsigned short* Bhs = lds + (ASPLIT ? 8192 : 4096);
    unsigned short* Bls = lds + (ASPLIT ? 12288 : 8192);

    int tid = threadIdx.x;
    int bm = blockIdx.x * 128;
    int bn = blockIdx.y * 128;
    int wid = tid >> 6, lane = tid & 63;
    int wm = wid & 1, wn = wid >> 1;
    int lrow = lane & 15, quad = lane >> 4;

    f32x4 acc[4][4];
#pragma unroll
    for (int mi = 0; mi < 4; mi++)
#pragma unroll
        for (int ni = 0; ni < 4; ni++) acc[mi][ni] = (f32x4){0.f, 0.f, 0.f, 0.f};

    for (int k0 = 0; k0 < K; k0 += 32) {
#pragma unroll
        for (int i = 0; i < NT * 2; i++) {
            int c = tid + 256 * i;
            int tile = c >> 9;
            int w = c & 511;
            int row = w >> 2;
            int part = w & 3;
            const unsigned short* g;
            if (ASPLIT) {
                if (tile == 0)      g = Ah + (size_t)(bm + row) * K + k0 + part * 8;
                else if (tile == 1) g = Al + (size_t)(bm + row) * K + k0 + part * 8;
                else if (tile == 2) g = Bh + (size_t)(bn + row) * K + k0 + part * 8;
                else                g = Bl + (size_t)(bn + row) * K + k0 + part * 8;
            } else {
                if (tile == 0)      g = Ah + (size_t)(bm + row) * K + k0 + part * 8;
                else if (tile == 1) g = Bh + (size_t)(bn + row) * K + k0 + part * 8;
                else                g = Bl + (size_t)(bn + row) * K + k0 + part * 8;
            }
            ulonglong2 v = *(const ulonglong2*)g;
            *(ulonglong2*)&lds[(tile << 12) + row * 32 + part * 8] = v;
        }
        __syncthreads();

        bf16x8 ah[4], al[4], bh[4], bl[4];
#pragma unroll
        for (int mi = 0; mi < 4; mi++) {
            int r = wm * 64 + mi * 16 + lrow;
            ah[mi] = *(const bf16x8*)&Ahs[r * 32 + quad * 8];
            if (ASPLIT) al[mi] = *(const bf16x8*)&Als[r * 32 + quad * 8];
        }
#pragma unroll
        for (int ni = 0; ni < 4; ni++) {
            int r = wn * 64 + ni * 16 + lrow;
            bh[ni] = *(const bf16x8*)&Bhs[r * 32 + quad * 8];
            bl[ni] = *(const bf16x8*)&Bls[r * 32 + quad * 8];
        }
#pragma unroll
        for (int mi = 0; mi < 4; mi++)
#pragma unroll
            for (int ni = 0; ni < 4; ni++) {
                acc[mi][ni] = __builtin_amdgcn_mfma_f32_16x16x32_bf16(ah[mi], bh[ni], acc[mi][ni], 0, 0, 0);
                acc[mi][ni] = __builtin_amdgcn_mfma_f32_16x16x32_bf16(ah[mi], bl[ni], acc[mi][ni], 0, 0, 0);
                if (ASPLIT)
                    acc[mi][ni] = __builtin_amdgcn_mfma_f32_16x16x32_bf16(al[mi], bh[ni], acc[mi][ni], 0, 0, 0);
            }
        __syncthreads();
    }

    float bv[4];
#pragma unroll
    for (int ni = 0; ni < 4; ni++) bv[ni] = bias[bn + wn * 64 + ni * 16 + lrow];
#pragma unroll
    for (int mi = 0; mi < 4; mi++) {
        int row0 = bm + wm * 64 + mi * 16 + quad * 4;
        float dsc[4];
        if (SCALEOUT) {
#pragma unroll
            for (int r = 0; r < 4; r++)
                dsc[r] = (row0 + r < N_NODES) ? dscale[row0 + r] : 0.f;
        }
#pragma unroll
        for (int ni = 0; ni < 4; ni++) {
            int col = bn + wn * 64 + ni * 16 + lrow;
#pragma unroll
            for (int r = 0; r < 4; r++) {
                int row = row0 + r;
                if (row < N_NODES) {
                    float v = fmaxf(acc[mi][ni][r] + bv[ni], 0.f);
                    if (SCALEOUT) v *= dsc[r];
                    Cout[(size_t)row * 256 + col] = f2bf(v);
                }
            }
        }
    }
}

// ---------------- fused mean-pool (batch sorted, h in bf16) + MLP head ----------
// Row loop unrolled x4 with independent accumulators: 4 loads in flight
// instead of a serial latency chain (one 512B coalesced read per row).
__global__ __launch_bounds__(256) void pool_mlp_kernel(const unsigned short* __restrict__ h,
                                                       const int* __restrict__ batch,
                                                       const float* __restrict__ Wf1,
                                                       const float* __restrict__ bf1,
                                                       const float* __restrict__ Wf2,
                                                       const float* __restrict__ bf2,
                                                       float* __restrict__ out) {
    int g = blockIdx.x;
    int t = threadIdx.x;  // 0..255
    __shared__ int bounds[2];
    if (t < 2) {
        int target = g + t;
        int lo = 0, hi = N_NODES;
        while (lo < hi) {
            int mid = (lo + hi) >> 1;
            if (batch[mid] < target) lo = mid + 1;
            else hi = mid;
        }
        bounds[t] = lo;
    }
    __syncthreads();
    int lo = bounds[0], hi = bounds[1];

    float a0 = 0.f, a1 = 0.f, a2 = 0.f, a3 = 0.f;
    int n = lo;
    for (; n + 4 <= hi; n += 4) {
        unsigned short v0 = h[(size_t)n * HID + t];
        unsigned short v1 = h[(size_t)(n + 1) * HID + t];
        unsigned short v2 = h[(size_t)(n + 2) * HID + t];
        unsigned short v3 = h[(size_t)(n + 3) * HID + t];
        a0 += bf2f(v0); a1 += bf2f(v1); a2 += bf2f(v2); a3 += bf2f(v3);
    }
    for (; n < hi; n++) a0 += bf2f(h[(size_t)n * HID + t]);
    float acc = (a0 + a1) + (a2 + a3);
    float inv = (hi > lo) ? 1.0f / (float)(hi - lo) : 0.f;
    __shared__ float p[256];
    p[t] = acc * inv;
    __syncthreads();

    float hv = 0.f;
    if (t < 128) {
        float a = bf1[t];
#pragma unroll 8
        for (int k = 0; k < 256; k++) a = fmaf(p[k], Wf1[k * 128 + t], a);
        hv = fmaxf(a, 0.f) * Wf2[t];
    }
#pragma unroll
    for (int off = 32; off > 0; off >>= 1) hv += __shfl_down(hv, off, 64);
    __shared__ float partial[4];
    if ((t & 63) == 0) partial[t >> 6] = hv;
    __syncthreads();
    if (t == 0) out[g] = partial[0] + partial[1] + bf2[0];
}

extern "C" void kernel_launch(void* const* d_in, const int* in_sizes, int n_in,
                              void* d_out, int out_size, void* d_ws, size_t ws_size,
                              hipStream_t stream) {
    const float* x   = (const float*)d_in[0];
    const int*   ei  = (const int*)d_in[1];
    const int*   bat = (const int*)d_in[2];
    const float* W1  = (const float*)d_in[3];
    const float* b1  = (const float*)d_in[4];
    const float* W2  = (const float*)d_in[5];
    const float* b2  = (const float*)d_in[6];
    const float* Wf1 = (const float*)d_in[7];
    const float* bf1 = (const float*)d_in[8];
    const float* Wf2 = (const float*)d_in[9];
    const float* bf2 = (const float*)d_in[10];
    float* out = (float*)d_out;

    char* ws = (char*)d_ws;
    // layout (peak end 0x9B20000 = 162.5 MB):
    //   0x0000000 deg        0x0080000 dinv      0x0100000 rowptr
    //   0x01F0000 bsum
    //   0x0200000 esrc (6.4 MB)
    //   0x0820000 W1th  0x0830000 W1tl  0x0840000 W2th  0x0860000 W2tl
    //   0x0880000 A1h (25.6 MB) / later A2 (51.2 MB, single)
    //   0x20F0000 eord (6.4 MB, dead after fill) -> A1l (25.6 MB)  [A2 overlaps]
    //   0x6A40000 xbf (25.6 MB) -> H1bf (51.2 MB) -> H2bf (51.2 MB) time-multiplexed
    int*   deg    = (int*)(ws);
    float* dinv   = (float*)(ws + 0x0080000);
    int*   rowptr = (int*)(ws + 0x0100000);
    int*   bsum   = (int*)(ws + 0x01F0000);
    int*   esrc   = (int*)(ws + 0x0200000);
    unsigned short* W1th = (unsigned short*)(ws + 0x0820000);
    unsigned short* W1tl = (unsigned short*)(ws + 0x0830000);
    unsigned short* W2th = (unsigned short*)(ws + 0x0840000);
    unsigned short* W2tl = (unsigned short*)(ws + 0x0860000);
    unsigned short* A1h  = (unsigned short*)(ws + 0x0880000);
    int*   eord   = (int*)(ws + 0x20F0000);                    // dead before A1l written
    unsigned short* A1l  = (unsigned short*)(ws + 0x20F0000);
    unsigned short* A2   = (unsigned short*)(ws + 0x0880000);  // reuses A1h+A1l space
    unsigned short* xbf  = (unsigned short*)(ws + 0x6A40000);
    unsigned short* H1bf = (unsigned short*)(ws + 0x6A40000);  // overwrites dead xbf
    unsigned short* H2bf = (unsigned short*)(ws + 0x6A40000);  // overwrites dead H1bf
    (void)ws_size;

    hipMemsetAsync(deg, 0, (size_t)N_NODES * sizeof(int), stream);

    // CSR build front half (produces dinv needed by the prescaled x2bf)
    count_deg_kernel<<<(N_EDGES + 255) / 256, 256, 0, stream>>>(ei, deg, eord);
    blocksum_kernel<<<SCAN_BLOCKS, 1024, 0, stream>>>(deg, bsum, dinv);

    // prep (x2bf now consumes dinv for the prescale)
    x2bf_kernel<<<(N_NODES * IN_DIM / 4) / 256, 256, 0, stream>>>(x, dinv, xbf);
    wsplit_all_kernel<<<((IN_DIM + HID) * 256) / 256, 256, 0, stream>>>(W1, W2, W1th, W1tl, W2th, W2tl);

    // CSR build back half
    bscan_kernel<<<1, 128, 0, stream>>>(bsum);
    scanout_kernel<<<SCAN_BLOCKS, 1024, 0, stream>>>(deg, bsum, rowptr);
    fill_kernel<<<(N_EDGES + 255) / 256, 256, 0, stream>>>(ei, rowptr, eord, esrc);

    // layer 1: A1 = split(ddst * sum X'); H1' = dinv * relu(A1 @ W1 + b1)  [3-term]
    agg128_kernel<<<N_NODES / 4, 256, 0, stream>>>(xbf, esrc, rowptr, dinv, A1h, A1l);
    {
        dim3 grid(M_PAD / 128, 2);
        mfma_gemm_bias_relu<IN_DIM, true, true><<<grid, 256, 0, stream>>>(A1h, A1l, W1th, W1tl, b1, dinv, H1bf);
    }

    // layer 2: A2 = bf16(ddst * sum H1'); H2 = relu(A2 @ W2 + b2)  [2-term]
    agg256_kernel<<<N_NODES / 4, 256, 0, stream>>>(H1bf, esrc, rowptr, dinv, A2);
    {
        dim3 grid(M_PAD / 128, 2);
        mfma_gemm_bias_relu<HID, false, false><<<grid, 256, 0, stream>>>(A2, nullptr, W2th, W2tl, b2, nullptr, H2bf);
    }

    // pooling + MLP head (bf16 h)
    pool_mlp_kernel<<<NUM_GRAPHS, 256, 0, stream>>>(H2bf, bat, Wf1, bf1, Wf2, bf2, out);
}

// Round 8
// 536.624 us; speedup vs baseline: 1.0284x; 1.0188x over previous
//
#include <hip/hip_runtime.h>
#include <hip/hip_bf16.h>

#define N_NODES 100000
#define N_EDGES 1600000
#define IN_DIM 128
#define HID 256
#define NUM_GRAPHS 2048
#define M_PAD 100096  // 782 * 128
#define SCAN_BLOCKS 98  // ceil(100000/1024)

typedef __bf16 bf16x8 __attribute__((ext_vector_type(8)));
typedef float f32x4 __attribute__((ext_vector_type(4)));

typedef const void __attribute__((address_space(1))) gvoid_t;
typedef void __attribute__((address_space(3))) svoid_t;

__device__ inline unsigned short f2bf(float x) {
    union { __hip_bfloat16 h; unsigned short u; } v;
    v.h = __float2bfloat16(x);
    return v.u;
}
__device__ inline float bf2f(unsigned short u) {
    return __uint_as_float(((unsigned int)u) << 16);
}
__device__ inline int rfl(int x) { return __builtin_amdgcn_readfirstlane(x); }

// ---------------- degree histogram over dst + per-edge ordinal ----------------
__global__ void count_deg_kernel(const int* __restrict__ ei, int* __restrict__ deg,
                                 int* __restrict__ eord) {
    int e = blockIdx.x * blockDim.x + threadIdx.x;
    if (e < N_EDGES) {
        eord[e] = atomicAdd(&deg[ei[N_EDGES + e]], 1);
    }
}

// ---------------- block sums (+ fused dinv) ----------------
__global__ __launch_bounds__(1024) void blocksum_kernel(const int* __restrict__ deg,
                                                        int* __restrict__ bsum,
                                                        float* __restrict__ dinv) {
    int i = blockIdx.x * 1024 + threadIdx.x;
    int v = (i < N_NODES) ? deg[i] : 0;
    if (i < N_NODES) dinv[i] = rsqrtf((float)(v + 1));  // self-loop adds 1
    __shared__ int s[1024];
    int t = threadIdx.x;
    s[t] = v;
    __syncthreads();
#pragma unroll
    for (int off = 512; off > 0; off >>= 1) {
        if (t < off) s[t] += s[t + off];
        __syncthreads();
    }
    if (t == 0) bsum[blockIdx.x] = s[0];
}

__global__ __launch_bounds__(128) void bscan_kernel(int* __restrict__ bsum) {
    __shared__ int s[128];
    int t = threadIdx.x;
    int v = (t < SCAN_BLOCKS) ? bsum[t] : 0;
    s[t] = v;
    __syncthreads();
#pragma unroll
    for (int off = 1; off < 128; off <<= 1) {
        int x = (t >= off) ? s[t - off] : 0;
        __syncthreads();
        s[t] += x;
        __syncthreads();
    }
    if (t < SCAN_BLOCKS) bsum[t] = (t > 0) ? s[t - 1] : 0;  // exclusive
}

__global__ __launch_bounds__(1024) void scanout_kernel(const int* __restrict__ deg,
                                                       const int* __restrict__ bsum,
                                                       int* __restrict__ rowptr) {
    int i = blockIdx.x * 1024 + threadIdx.x;
    int t = threadIdx.x;
    int v = (i < N_NODES) ? deg[i] : 0;
    __shared__ int s[1024];
    s[t] = v;
    __syncthreads();
#pragma unroll
    for (int off = 1; off < 1024; off <<= 1) {
        int x = (t >= off) ? s[t - off] : 0;
        __syncthreads();
        s[t] += x;
        __syncthreads();
    }
    int base = bsum[blockIdx.x];
    int excl = (t > 0) ? s[t - 1] : 0;
    if (i < N_NODES) rowptr[i] = base + excl;
    if (i == N_NODES - 1) rowptr[N_NODES] = base + s[t];
}

// ---------------- bucket fill: CSR src list sorted by dst (atomic-free) ----------
__global__ void fill_kernel(const int* __restrict__ ei, const int* __restrict__ rowptr,
                            const int* __restrict__ eord, int* __restrict__ esrc) {
    int e = blockIdx.x * blockDim.x + threadIdx.x;
    if (e < N_EDGES) {
        int dst = ei[N_EDGES + e];
        esrc[rowptr[dst] + eord[e]] = ei[e];
    }
}

// ---------------- x -> bf16, prescaled by dinv[row] ----------------
__global__ void x2bf_kernel(const float* __restrict__ x, const float* __restrict__ dinv,
                            unsigned short* __restrict__ xb) {
    size_t i = ((size_t)blockIdx.x * 256 + threadIdx.x) * 4;
    int node = (int)(i >> 7);  // 128 floats per row
    float dv = dinv[node];
    float4 v = *(const float4*)(x + i);
    ushort4 o;
    o.x = f2bf(v.x * dv); o.y = f2bf(v.y * dv);
    o.z = f2bf(v.z * dv); o.w = f2bf(v.w * dv);
    *(ushort4*)(xb + i) = o;
}

// ---------------- both weight transposes + bf16 splits in one launch ----------
__global__ void wsplit_all_kernel(const float* __restrict__ W1, const float* __restrict__ W2,
                                  unsigned short* __restrict__ W1th, unsigned short* __restrict__ W1tl,
                                  unsigned short* __restrict__ W2th, unsigned short* __restrict__ W2tl) {
    int idx = blockIdx.x * 256 + threadIdx.x;
    if (idx < IN_DIM * 256) {
        int k = idx >> 8, n = idx & 255;
        float w = W1[idx];
        unsigned short h = f2bf(w);
        unsigned short l = f2bf(w - bf2f(h));
        W1th[n * IN_DIM + k] = h;
        W1tl[n * IN_DIM + k] = l;
    } else {
        int i2 = idx - IN_DIM * 256;
        int k = i2 >> 8, n = i2 & 255;
        float w = W2[i2];
        unsigned short h = f2bf(w);
        unsigned short l = f2bf(w - bf2f(h));
        W2th[n * HID + k] = h;
        W2tl[n * HID + k] = l;
    }
}

// ---------------- gather agg 128-dim from prescaled bf16, hi/lo out ----------
// A[dst] = ddst * ( X'[dst] + sum_src X'[src] ); X' already carries dinv[src].
// Plain stores (NOT non-temporal): A1 is re-read by GEMM1 within ~100us,
// keep it L3-resident (r6 post-mortem: NT stores cost ~+12us on the GEMMs).
__global__ __launch_bounds__(256) void agg128_kernel(const unsigned short* __restrict__ X,
                                                     const int* __restrict__ esrc,
                                                     const int* __restrict__ rowptr,
                                                     const float* __restrict__ dinv,
                                                     unsigned short* __restrict__ Ah,
                                                     unsigned short* __restrict__ Al) {
    int node = rfl(blockIdx.x * 4 + (threadIdx.x >> 6));
    int lane = threadIdx.x & 63;
    float ddst = dinv[node];
    int s = rfl(rowptr[node]);
    int e = rfl(rowptr[node + 1]);

    ushort2 h0 = *((const ushort2*)(X + (size_t)node * 128) + lane);
    float2 acc = make_float2(bf2f(h0.x), bf2f(h0.y));

    int j = s;
    for (; j + 8 <= e; j += 8) {
        int si[8];
#pragma unroll
        for (int u = 0; u < 8; u++) si[u] = rfl(esrc[j + u]);
        ushort2 xv[8];
#pragma unroll
        for (int u = 0; u < 8; u++)
            xv[u] = *((const ushort2*)(X + (size_t)si[u] * 128) + lane);
#pragma unroll
        for (int u = 0; u < 8; u++) {
            acc.x += bf2f(xv[u].x);
            acc.y += bf2f(xv[u].y);
        }
    }
    for (; j + 4 <= e; j += 4) {
        int si[4];
#pragma unroll
        for (int u = 0; u < 4; u++) si[u] = rfl(esrc[j + u]);
        ushort2 xv[4];
#pragma unroll
        for (int u = 0; u < 4; u++)
            xv[u] = *((const ushort2*)(X + (size_t)si[u] * 128) + lane);
#pragma unroll
        for (int u = 0; u < 4; u++) {
            acc.x += bf2f(xv[u].x);
            acc.y += bf2f(xv[u].y);
        }
    }
    for (; j < e; j++) {
        int src = rfl(esrc[j]);
        ushort2 xv = *((const ushort2*)(X + (size_t)src * 128) + lane);
        acc.x += bf2f(xv.x);
        acc.y += bf2f(xv.y);
    }
    acc.x *= ddst;
    acc.y *= ddst;
    size_t o = (size_t)node * 128 + lane * 2;
    ushort2 hi, lo;
    hi.x = f2bf(acc.x); lo.x = f2bf(acc.x - bf2f(hi.x));
    hi.y = f2bf(acc.y); lo.y = f2bf(acc.y - bf2f(hi.y));
    *(ushort2*)(Ah + o) = hi;
    *(ushort2*)(Al + o) = lo;
}

// ---------------- gather agg 256-dim from prescaled bf16, hi out ----------
__global__ __launch_bounds__(256) void agg256_kernel(const unsigned short* __restrict__ H,
                                                     const int* __restrict__ esrc,
                                                     const int* __restrict__ rowptr,
                                                     const float* __restrict__ dinv,
                                                     unsigned short* __restrict__ Ah) {
    int node = rfl(blockIdx.x * 4 + (threadIdx.x >> 6));
    int lane = threadIdx.x & 63;
    float ddst = dinv[node];
    int s = rfl(rowptr[node]);
    int e = rfl(rowptr[node + 1]);

    ushort4 h0 = *((const ushort4*)(H + (size_t)node * 256) + lane);
    float4 acc = make_float4(bf2f(h0.x), bf2f(h0.y), bf2f(h0.z), bf2f(h0.w));

    int j = s;
    for (; j + 8 <= e; j += 8) {
        int si[8];
#pragma unroll
        for (int u = 0; u < 8; u++) si[u] = rfl(esrc[j + u]);
        ushort4 xv[8];
#pragma unroll
        for (int u = 0; u < 8; u++)
            xv[u] = *((const ushort4*)(H + (size_t)si[u] * 256) + lane);
#pragma unroll
        for (int u = 0; u < 8; u++) {
            acc.x += bf2f(xv[u].x);
            acc.y += bf2f(xv[u].y);
            acc.z += bf2f(xv[u].z);
            acc.w += bf2f(xv[u].w);
        }
    }
    for (; j + 4 <= e; j += 4) {
        int si[4];
#pragma unroll
        for (int u = 0; u < 4; u++) si[u] = rfl(esrc[j + u]);
        ushort4 xv[4];
#pragma unroll
        for (int u = 0; u < 4; u++)
            xv[u] = *((const ushort4*)(H + (size_t)si[u] * 256) + lane);
#pragma unroll
        for (int u = 0; u < 4; u++) {
            acc.x += bf2f(xv[u].x);
            acc.y += bf2f(xv[u].y);
            acc.z += bf2f(xv[u].z);
            acc.w += bf2f(xv[u].w);
        }
    }
    for (; j < e; j++) {
        int src = rfl(esrc[j]);
        ushort4 xv = *((const ushort4*)(H + (size_t)src * 256) + lane);
        acc.x += bf2f(xv.x);
        acc.y += bf2f(xv.y);
        acc.z += bf2f(xv.z);
        acc.w += bf2f(xv.w);
    }
    acc.x *= ddst; acc.y *= ddst; acc.z *= ddst; acc.w *= ddst;
    size_t o = (size_t)node * 256 + lane * 4;
    ushort4 hi;
    hi.x = f2bf(acc.x); hi.y = f2bf(acc.y);
    hi.z = f2bf(acc.z); hi.w = f2bf(acc.w);
    *(ushort4*)(Ah + o) = hi;
}

// ---------------- MFMA GEMM: C = relu(A @ W + b) [optionally * dinv[row]] ------
// ASPLIT: A has hi+lo (3-term product) else hi only (2-term). Output bf16.
// SCALEOUT: multiply output row by dscale[row] (prescale for next gather).
// Staging now uses width-16 global_load_lds (direct HBM->LDS, no VGPR round
// trip). LDS layout is byte-contiguous in c=tid+256*i (verified across row and
// tile boundaries: tile stride = 8192 B exactly), so each wave's destination is
// wave-uniform base + lane*16 as the instruction requires; global src per-lane.
template <int K, bool ASPLIT, bool SCALEOUT>
__launch_bounds__(256, 2)
__global__ void mfma_gemm_bias_relu(const unsigned short* __restrict__ Ah,
                                    const unsigned short* __restrict__ Al,
                                    const unsigned short* __restrict__ Bh,
                                    const unsigned short* __restrict__ Bl,
                                    const float* __restrict__ bias,
                                    const float* __restrict__ dscale,
                                    unsigned short* __restrict__ Cout) {
    constexpr int NT = ASPLIT ? 4 : 3;
    __shared__ __align__(16) unsigned short lds[NT * 128 * 32];
    unsigned short* Ahs = lds;
    unsigned short* Als = lds + 4096;                    // only valid if ASPLIT
    unsigned short* Bhs = lds + (ASPLIT ? 8192 : 4096);
    unsigned short* Bls = lds + (ASPLIT ? 12288 : 8192);

    int tid = threadIdx.x;
    int bm = blockIdx.x * 128;
    int bn = blockIdx.y * 128;
    int wid = tid >> 6, lane = tid & 63;
    int wm = wid & 1, wn = wid >> 1;
    int lrow = lane & 15, quad = lane >> 4;

    f32x4 acc[4][4];
#pragma unroll
    for (int mi = 0; mi < 4; mi++)
#pragma unroll
        for (int ni = 0; ni < 4; ni++) acc[mi][ni] = (f32x4){0.f, 0.f, 0.f, 0.f};

    for (int k0 = 0; k0 < K; k0 += 32) {
#pragma unroll
        for (int i = 0; i < NT * 2; i++) {
            int c = tid + 256 * i;
            int tile = c >> 9;
            int w = c & 511;
            int row = w >> 2;
            int part = w & 3;
            const unsigned short* g;
            if (ASPLIT) {
                if (tile == 0)      g = Ah + (size_t)(bm + row) * K + k0 + part * 8;
                else if (tile == 1) g = Al + (size_t)(bm + row) * K + k0 + part * 8;
                else if (tile == 2) g = Bh + (size_t)(bn + row) * K + k0 + part * 8;
                else                g = Bl + (size_t)(bn + row) * K + k0 + part * 8;
            } else {
                if (tile == 0)      g = Ah + (size_t)(bm + row) * K + k0 + part * 8;
                else if (tile == 1) g = Bh + (size_t)(bn + row) * K + k0 + part * 8;
                else                g = Bl + (size_t)(bn + row) * K + k0 + part * 8;
            }
            __builtin_amdgcn_global_load_lds(
                (gvoid_t*)g,
                (svoid_t*)((char*)lds + (size_t)c * 16),
                16, 0, 0);
        }
        __syncthreads();

        bf16x8 ah[4], al[4], bh[4], bl[4];
#pragma unroll
        for (int mi = 0; mi < 4; mi++) {
            int r = wm * 64 + mi * 16 + lrow;
            ah[mi] = *(const bf16x8*)&Ahs[r * 32 + quad * 8];
            if (ASPLIT) al[mi] = *(const bf16x8*)&Als[r * 32 + quad * 8];
        }
#pragma unroll
        for (int ni = 0; ni < 4; ni++) {
            int r = wn * 64 + ni * 16 + lrow;
            bh[ni] = *(const bf16x8*)&Bhs[r * 32 + quad * 8];
            bl[ni] = *(const bf16x8*)&Bls[r * 32 + quad * 8];
        }
#pragma unroll
        for (int mi = 0; mi < 4; mi++)
#pragma unroll
            for (int ni = 0; ni < 4; ni++) {
                acc[mi][ni] = __builtin_amdgcn_mfma_f32_16x16x32_bf16(ah[mi], bh[ni], acc[mi][ni], 0, 0, 0);
                acc[mi][ni] = __builtin_amdgcn_mfma_f32_16x16x32_bf16(ah[mi], bl[ni], acc[mi][ni], 0, 0, 0);
                if (ASPLIT)
                    acc[mi][ni] = __builtin_amdgcn_mfma_f32_16x16x32_bf16(al[mi], bh[ni], acc[mi][ni], 0, 0, 0);
            }
        __syncthreads();
    }

    float bv[4];
#pragma unroll
    for (int ni = 0; ni < 4; ni++) bv[ni] = bias[bn + wn * 64 + ni * 16 + lrow];
#pragma unroll
    for (int mi = 0; mi < 4; mi++) {
        int row0 = bm + wm * 64 + mi * 16 + quad * 4;
        float dsc[4];
        if (SCALEOUT) {
#pragma unroll
            for (int r = 0; r < 4; r++)
                dsc[r] = (row0 + r < N_NODES) ? dscale[row0 + r] : 0.f;
        }
#pragma unroll
        for (int ni = 0; ni < 4; ni++) {
            int col = bn + wn * 64 + ni * 16 + lrow;
#pragma unroll
            for (int r = 0; r < 4; r++) {
                int row = row0 + r;
                if (row < N_NODES) {
                    float v = fmaxf(acc[mi][ni][r] + bv[ni], 0.f);
                    if (SCALEOUT) v *= dsc[r];
                    Cout[(size_t)row * 256 + col] = f2bf(v);
                }
            }
        }
    }
}

// ---------------- fused mean-pool (batch sorted, h in bf16) + MLP head ----------
__global__ __launch_bounds__(256) void pool_mlp_kernel(const unsigned short* __restrict__ h,
                                                       const int* __restrict__ batch,
                                                       const float* __restrict__ Wf1,
                                                       const float* __restrict__ bf1,
                                                       const float* __restrict__ Wf2,
                                                       const float* __restrict__ bf2,
                                                       float* __restrict__ out) {
    int g = blockIdx.x;
    int t = threadIdx.x;  // 0..255
    __shared__ int bounds[2];
    if (t < 2) {
        int target = g + t;
        int lo = 0, hi = N_NODES;
        while (lo < hi) {
            int mid = (lo + hi) >> 1;
            if (batch[mid] < target) lo = mid + 1;
            else hi = mid;
        }
        bounds[t] = lo;
    }
    __syncthreads();
    int lo = bounds[0], hi = bounds[1];

    float a0 = 0.f, a1 = 0.f, a2 = 0.f, a3 = 0.f;
    int n = lo;
    for (; n + 4 <= hi; n += 4) {
        unsigned short v0 = h[(size_t)n * HID + t];
        unsigned short v1 = h[(size_t)(n + 1) * HID + t];
        unsigned short v2 = h[(size_t)(n + 2) * HID + t];
        unsigned short v3 = h[(size_t)(n + 3) * HID + t];
        a0 += bf2f(v0); a1 += bf2f(v1); a2 += bf2f(v2); a3 += bf2f(v3);
    }
    for (; n < hi; n++) a0 += bf2f(h[(size_t)n * HID + t]);
    float acc = (a0 + a1) + (a2 + a3);
    float inv = (hi > lo) ? 1.0f / (float)(hi - lo) : 0.f;
    __shared__ float p[256];
    p[t] = acc * inv;
    __syncthreads();

    float hv = 0.f;
    if (t < 128) {
        float a = bf1[t];
#pragma unroll 8
        for (int k = 0; k < 256; k++) a = fmaf(p[k], Wf1[k * 128 + t], a);
        hv = fmaxf(a, 0.f) * Wf2[t];
    }
#pragma unroll
    for (int off = 32; off > 0; off >>= 1) hv += __shfl_down(hv, off, 64);
    __shared__ float partial[4];
    if ((t & 63) == 0) partial[t >> 6] = hv;
    __syncthreads();
    if (t == 0) out[g] = partial[0] + partial[1] + bf2[0];
}

extern "C" void kernel_launch(void* const* d_in, const int* in_sizes, int n_in,
                              void* d_out, int out_size, void* d_ws, size_t ws_size,
                              hipStream_t stream) {
    const float* x   = (const float*)d_in[0];
    const int*   ei  = (const int*)d_in[1];
    const int*   bat = (const int*)d_in[2];
    const float* W1  = (const float*)d_in[3];
    const float* b1  = (const float*)d_in[4];
    const float* W2  = (const float*)d_in[5];
    const float* b2  = (const float*)d_in[6];
    const float* Wf1 = (const float*)d_in[7];
    const float* bf1 = (const float*)d_in[8];
    const float* Wf2 = (const float*)d_in[9];
    const float* bf2 = (const float*)d_in[10];
    float* out = (float*)d_out;

    char* ws = (char*)d_ws;
    // layout (peak end 0x9B20000 = 162.5 MB):
    //   0x0000000 deg        0x0080000 dinv      0x0100000 rowptr
    //   0x01F0000 bsum
    //   0x0200000 esrc (6.4 MB)
    //   0x0820000 W1th  0x0830000 W1tl  0x0840000 W2th  0x0860000 W2tl
    //   0x0880000 A1h (25.6 MB) / later A2 (51.2 MB, single)
    //   0x20F0000 eord (6.4 MB, dead after fill) -> A1l (25.6 MB)  [A2 overlaps]
    //   0x6A40000 xbf (25.6 MB) -> H1bf (51.2 MB) -> H2bf (51.2 MB) time-multiplexed
    int*   deg    = (int*)(ws);
    float* dinv   = (float*)(ws + 0x0080000);
    int*   rowptr = (int*)(ws + 0x0100000);
    int*   bsum   = (int*)(ws + 0x01F0000);
    int*   esrc   = (int*)(ws + 0x0200000);
    unsigned short* W1th = (unsigned short*)(ws + 0x0820000);
    unsigned short* W1tl = (unsigned short*)(ws + 0x0830000);
    unsigned short* W2th = (unsigned short*)(ws + 0x0840000);
    unsigned short* W2tl = (unsigned short*)(ws + 0x0860000);
    unsigned short* A1h  = (unsigned short*)(ws + 0x0880000);
    int*   eord   = (int*)(ws + 0x20F0000);                    // dead before A1l written
    unsigned short* A1l  = (unsigned short*)(ws + 0x20F0000);
    unsigned short* A2   = (unsigned short*)(ws + 0x0880000);  // reuses A1h+A1l space
    unsigned short* xbf  = (unsigned short*)(ws + 0x6A40000);
    unsigned short* H1bf = (unsigned short*)(ws + 0x6A40000);  // overwrites dead xbf
    unsigned short* H2bf = (unsigned short*)(ws + 0x6A40000);  // overwrites dead H1bf
    (void)ws_size;

    hipMemsetAsync(deg, 0, (size_t)N_NODES * sizeof(int), stream);

    // CSR build front half (produces dinv needed by the prescaled x2bf)
    count_deg_kernel<<<(N_EDGES + 255) / 256, 256, 0, stream>>>(ei, deg, eord);
    blocksum_kernel<<<SCAN_BLOCKS, 1024, 0, stream>>>(deg, bsum, dinv);

    // prep (x2bf consumes dinv for the prescale)
    x2bf_kernel<<<(N_NODES * IN_DIM / 4) / 256, 256, 0, stream>>>(x, dinv, xbf);
    wsplit_all_kernel<<<((IN_DIM + HID) * 256) / 256, 256, 0, stream>>>(W1, W2, W1th, W1tl, W2th, W2tl);

    // CSR build back half
    bscan_kernel<<<1, 128, 0, stream>>>(bsum);
    scanout_kernel<<<SCAN_BLOCKS, 1024, 0, stream>>>(deg, bsum, rowptr);
    fill_kernel<<<(N_EDGES + 255) / 256, 256, 0, stream>>>(ei, rowptr, eord, esrc);

    // layer 1: A1 = split(ddst * sum X'); H1' = dinv * relu(A1 @ W1 + b1)  [3-term]
    agg128_kernel<<<N_NODES / 4, 256, 0, stream>>>(xbf, esrc, rowptr, dinv, A1h, A1l);
    {
        dim3 grid(M_PAD / 128, 2);
        mfma_gemm_bias_relu<IN_DIM, true, true><<<grid, 256, 0, stream>>>(A1h, A1l, W1th, W1tl, b1, dinv, H1bf);
    }

    // layer 2: A2 = bf16(ddst * sum H1'); H2 = relu(A2 @ W2 + b2)  [2-term]
    agg256_kernel<<<N_NODES / 4, 256, 0, stream>>>(H1bf, esrc, rowptr, dinv, A2);
    {
        dim3 grid(M_PAD / 128, 2);
        mfma_gemm_bias_relu<HID, false, false><<<grid, 256, 0, stream>>>(A2, nullptr, W2th, W2tl, b2, nullptr, H2bf);
    }

    // pooling + MLP head (bf16 h)
    pool_mlp_kernel<<<NUM_GRAPHS, 256, 0, stream>>>(H2bf, bat, Wf1, bf1, Wf2, bf2, out);
}

// Round 9
// 526.869 us; speedup vs baseline: 1.0474x; 1.0185x over previous
//
#include <hip/hip_runtime.h>
#include <hip/hip_bf16.h>

#define N_NODES 100000
#define N_EDGES 1600000
#define IN_DIM 128
#define HID 256
#define NUM_GRAPHS 2048
#define M_PAD 100096  // 782 * 128
#define SCAN_BLOCKS 98  // ceil(100000/1024)
#define X2BF_BLOCKS 12500  // N_NODES*IN_DIM/4/256

typedef __bf16 bf16x8 __attribute__((ext_vector_type(8)));
typedef float f32x4 __attribute__((ext_vector_type(4)));

typedef const void __attribute__((address_space(1))) gvoid_t;
typedef void __attribute__((address_space(3))) svoid_t;

__device__ inline unsigned short f2bf(float x) {
    union { __hip_bfloat16 h; unsigned short u; } v;
    v.h = __float2bfloat16(x);
    return v.u;
}
__device__ inline float bf2f(unsigned short u) {
    return __uint_as_float(((unsigned int)u) << 16);
}
__device__ inline int rfl(int x) { return __builtin_amdgcn_readfirstlane(x); }

// ---------------- degree histogram over dst + per-edge ordinal ----------------
__global__ void count_deg_kernel(const int* __restrict__ ei, int* __restrict__ deg,
                                 int* __restrict__ eord) {
    int e = blockIdx.x * blockDim.x + threadIdx.x;
    if (e < N_EDGES) {
        eord[e] = atomicAdd(&deg[ei[N_EDGES + e]], 1);
    }
}

// ---------------- block sums (+ fused dinv) ----------------
__global__ __launch_bounds__(1024) void blocksum_kernel(const int* __restrict__ deg,
                                                        int* __restrict__ bsum,
                                                        float* __restrict__ dinv) {
    int i = blockIdx.x * 1024 + threadIdx.x;
    int v = (i < N_NODES) ? deg[i] : 0;
    if (i < N_NODES) dinv[i] = rsqrtf((float)(v + 1));  // self-loop adds 1
    __shared__ int s[1024];
    int t = threadIdx.x;
    s[t] = v;
    __syncthreads();
#pragma unroll
    for (int off = 512; off > 0; off >>= 1) {
        if (t < off) s[t] += s[t + off];
        __syncthreads();
    }
    if (t == 0) bsum[blockIdx.x] = s[0];
}

// ---------------- scanout with inlined block-sum scan -----------------------
// Each block redundantly scans the 98 raw block sums in LDS (cheap) instead of
// a separate 1-block bscan launch that idled 255 CUs for a full launch+drain.
__global__ __launch_bounds__(1024) void scanout_kernel(const int* __restrict__ deg,
                                                       const int* __restrict__ bsum,
                                                       int* __restrict__ rowptr) {
    int t = threadIdx.x;
    __shared__ int bs[128];
    if (t < 128) bs[t] = (t < SCAN_BLOCKS) ? bsum[t] : 0;
    __syncthreads();
#pragma unroll
    for (int off = 1; off < 128; off <<= 1) {
        int x = 0;
        if (t < 128 && t >= off) x = bs[t - off];
        __syncthreads();
        if (t < 128) bs[t] += x;
        __syncthreads();
    }
    int base = (blockIdx.x > 0) ? bs[blockIdx.x - 1] : 0;

    int i = blockIdx.x * 1024 + t;
    int v = (i < N_NODES) ? deg[i] : 0;
    __shared__ int s[1024];
    s[t] = v;
    __syncthreads();
#pragma unroll
    for (int off = 1; off < 1024; off <<= 1) {
        int x = (t >= off) ? s[t - off] : 0;
        __syncthreads();
        s[t] += x;
        __syncthreads();
    }
    int excl = (t > 0) ? s[t - 1] : 0;
    if (i < N_NODES) rowptr[i] = base + excl;
    if (i == N_NODES - 1) rowptr[N_NODES] = base + s[t];
}

// ---------------- bucket fill: CSR src list sorted by dst (atomic-free) ----------
__global__ void fill_kernel(const int* __restrict__ ei, const int* __restrict__ rowptr,
                            const int* __restrict__ eord, int* __restrict__ esrc) {
    int e = blockIdx.x * blockDim.x + threadIdx.x;
    if (e < N_EDGES) {
        int dst = ei[N_EDGES + e];
        esrc[rowptr[dst] + eord[e]] = ei[e];
    }
}

// ---------------- merged prep: x->bf16 prescaled  +  weight transpose/split ----
__global__ void prep_kernel(const float* __restrict__ x, const float* __restrict__ dinv,
                            unsigned short* __restrict__ xb,
                            const float* __restrict__ W1, const float* __restrict__ W2,
                            unsigned short* __restrict__ W1th, unsigned short* __restrict__ W1tl,
                            unsigned short* __restrict__ W2th, unsigned short* __restrict__ W2tl) {
    int b = blockIdx.x;
    if (b < X2BF_BLOCKS) {
        size_t i = ((size_t)b * 256 + threadIdx.x) * 4;
        int node = (int)(i >> 7);  // 128 floats per row
        float dv = dinv[node];
        float4 v = *(const float4*)(x + i);
        ushort4 o;
        o.x = f2bf(v.x * dv); o.y = f2bf(v.y * dv);
        o.z = f2bf(v.z * dv); o.w = f2bf(v.w * dv);
        *(ushort4*)(xb + i) = o;
    } else {
        int idx = (b - X2BF_BLOCKS) * 256 + threadIdx.x;
        if (idx < IN_DIM * 256) {
            int k = idx >> 8, n = idx & 255;
            float w = W1[idx];
            unsigned short h = f2bf(w);
            unsigned short l = f2bf(w - bf2f(h));
            W1th[n * IN_DIM + k] = h;
            W1tl[n * IN_DIM + k] = l;
        } else {
            int i2 = idx - IN_DIM * 256;
            int k = i2 >> 8, n = i2 & 255;
            float w = W2[i2];
            unsigned short h = f2bf(w);
            unsigned short l = f2bf(w - bf2f(h));
            W2th[n * HID + k] = h;
            W2tl[n * HID + k] = l;
        }
    }
}

// ---------------- gather agg 128-dim from prescaled bf16, hi/lo out ----------
// A[dst] = ddst * ( X'[dst] + sum_src X'[src] ); X' already carries dinv[src].
__global__ __launch_bounds__(256) void agg128_kernel(const unsigned short* __restrict__ X,
                                                     const int* __restrict__ esrc,
                                                     const int* __restrict__ rowptr,
                                                     const float* __restrict__ dinv,
                                                     unsigned short* __restrict__ Ah,
                                                     unsigned short* __restrict__ Al) {
    int node = rfl(blockIdx.x * 4 + (threadIdx.x >> 6));
    int lane = threadIdx.x & 63;
    float ddst = dinv[node];
    int s = rfl(rowptr[node]);
    int e = rfl(rowptr[node + 1]);

    ushort2 h0 = *((const ushort2*)(X + (size_t)node * 128) + lane);
    float2 acc = make_float2(bf2f(h0.x), bf2f(h0.y));

    int j = s;
    for (; j + 8 <= e; j += 8) {
        int si[8];
#pragma unroll
        for (int u = 0; u < 8; u++) si[u] = rfl(esrc[j + u]);
        ushort2 xv[8];
#pragma unroll
        for (int u = 0; u < 8; u++)
            xv[u] = *((const ushort2*)(X + (size_t)si[u] * 128) + lane);
#pragma unroll
        for (int u = 0; u < 8; u++) {
            acc.x += bf2f(xv[u].x);
            acc.y += bf2f(xv[u].y);
        }
    }
    for (; j + 4 <= e; j += 4) {
        int si[4];
#pragma unroll
        for (int u = 0; u < 4; u++) si[u] = rfl(esrc[j + u]);
        ushort2 xv[4];
#pragma unroll
        for (int u = 0; u < 4; u++)
            xv[u] = *((const ushort2*)(X + (size_t)si[u] * 128) + lane);
#pragma unroll
        for (int u = 0; u < 4; u++) {
            acc.x += bf2f(xv[u].x);
            acc.y += bf2f(xv[u].y);
        }
    }
    for (; j < e; j++) {
        int src = rfl(esrc[j]);
        ushort2 xv = *((const ushort2*)(X + (size_t)src * 128) + lane);
        acc.x += bf2f(xv.x);
        acc.y += bf2f(xv.y);
    }
    acc.x *= ddst;
    acc.y *= ddst;
    size_t o = (size_t)node * 128 + lane * 2;
    ushort2 hi, lo;
    hi.x = f2bf(acc.x); lo.x = f2bf(acc.x - bf2f(hi.x));
    hi.y = f2bf(acc.y); lo.y = f2bf(acc.y - bf2f(hi.y));
    *(ushort2*)(Ah + o) = hi;
    *(ushort2*)(Al + o) = lo;
}

// ---------------- gather agg 256-dim from prescaled bf16, hi out ----------
__global__ __launch_bounds__(256) void agg256_kernel(const unsigned short* __restrict__ H,
                                                     const int* __restrict__ esrc,
                                                     const int* __restrict__ rowptr,
                                                     const float* __restrict__ dinv,
                                                     unsigned short* __restrict__ Ah) {
    int node = rfl(blockIdx.x * 4 + (threadIdx.x >> 6));
    int lane = threadIdx.x & 63;
    float ddst = dinv[node];
    int s = rfl(rowptr[node]);
    int e = rfl(rowptr[node + 1]);

    ushort4 h0 = *((const ushort4*)(H + (size_t)node * 256) + lane);
    float4 acc = make_float4(bf2f(h0.x), bf2f(h0.y), bf2f(h0.z), bf2f(h0.w));

    int j = s;
    for (; j + 8 <= e; j += 8) {
        int si[8];
#pragma unroll
        for (int u = 0; u < 8; u++) si[u] = rfl(esrc[j + u]);
        ushort4 xv[8];
#pragma unroll
        for (int u = 0; u < 8; u++)
            xv[u] = *((const ushort4*)(H + (size_t)si[u] * 256) + lane);
#pragma unroll
        for (int u = 0; u < 8; u++) {
            acc.x += bf2f(xv[u].x);
            acc.y += bf2f(xv[u].y);
            acc.z += bf2f(xv[u].z);
            acc.w += bf2f(xv[u].w);
        }
    }
    for (; j + 4 <= e; j += 4) {
        int si[4];
#pragma unroll
        for (int u = 0; u < 4; u++) si[u] = rfl(esrc[j + u]);
        ushort4 xv[4];
#pragma unroll
        for (int u = 0; u < 4; u++)
            xv[u] = *((const ushort4*)(H + (size_t)si[u] * 256) + lane);
#pragma unroll
        for (int u = 0; u < 4; u++) {
            acc.x += bf2f(xv[u].x);
            acc.y += bf2f(xv[u].y);
            acc.z += bf2f(xv[u].z);
            acc.w += bf2f(xv[u].w);
        }
    }
    for (; j < e; j++) {
        int src = rfl(esrc[j]);
        ushort4 xv = *((const ushort4*)(H + (size_t)src * 256) + lane);
        acc.x += bf2f(xv.x);
        acc.y += bf2f(xv.y);
        acc.z += bf2f(xv.z);
        acc.w += bf2f(xv.w);
    }
    acc.x *= ddst; acc.y *= ddst; acc.z *= ddst; acc.w *= ddst;
    size_t o = (size_t)node * 256 + lane * 4;
    ushort4 hi;
    hi.x = f2bf(acc.x); hi.y = f2bf(acc.y);
    hi.z = f2bf(acc.z); hi.w = f2bf(acc.w);
    *(ushort4*)(Ah + o) = hi;
}

// ---------------- MFMA GEMM: C = relu(A @ W + b) [optionally * dinv[row]] ------
// ASPLIT: A has hi+lo (3-term product) else hi only (2-term). Output bf16.
// SCALEOUT: multiply output row by dscale[row] (prescale for next gather).
// Staging via width-16 global_load_lds (r8, -10us).
// Grid is (16, 98): row = by*8 + (bx&7), col = bx>>3 -> the two blocks sharing
// an A-row-tile have linear IDs 8 apart (same XCD under round-robin, near in
// time), so the second A fetch hits L2/L3 hot instead of re-pulling from HBM.
// Rows 782..783 are pad: A reads land in allocated workspace, writes guarded.
template <int K, bool ASPLIT, bool SCALEOUT>
__launch_bounds__(256, 2)
__global__ void mfma_gemm_bias_relu(const unsigned short* __restrict__ Ah,
                                    const unsigned short* __restrict__ Al,
                                    const unsigned short* __restrict__ Bh,
                                    const unsigned short* __restrict__ Bl,
                                    const float* __restrict__ bias,
                                    const float* __restrict__ dscale,
                                    unsigned short* __restrict__ Cout) {
    constexpr int NT = ASPLIT ? 4 : 3;
    __shared__ __align__(16) unsigned short lds[NT * 128 * 32];
    unsigned short* Ahs = lds;
    unsigned short* Als = lds + 4096;                    // only valid if ASPLIT
    unsigned short* Bhs = lds + (ASPLIT ? 8192 : 4096);
    unsigned short* Bls = lds + (ASPLIT ? 12288 : 8192);

    int tid = threadIdx.x;
    int bm = (blockIdx.y * 8 + (blockIdx.x & 7)) * 128;
    int bn = (blockIdx.x >> 3) * 128;
    int wid = tid >> 6, lane = tid & 63;
    int wm = wid & 1, wn = wid >> 1;
    int lrow = lane & 15, quad = lane >> 4;

    f32x4 acc[4][4];
#pragma unroll
    for (int mi = 0; mi < 4; mi++)
#pragma unroll
        for (int ni = 0; ni < 4; ni++) acc[mi][ni] = (f32x4){0.f, 0.f, 0.f, 0.f};

    for (int k0 = 0; k0 < K; k0 += 32) {
#pragma unroll
        for (int i = 0; i < NT * 2; i++) {
            int c = tid + 256 * i;
            int tile = c >> 9;
            int w = c & 511;
            int row = w >> 2;
            int part = w & 3;
            const unsigned short* g;
            if (ASPLIT) {
                if (tile == 0)      g = Ah + (size_t)(bm + row) * K + k0 + part * 8;
                else if (tile == 1) g = Al + (size_t)(bm + row) * K + k0 + part * 8;
                else if (tile == 2) g = Bh + (size_t)(bn + row) * K + k0 + part * 8;
                else                g = Bl + (size_t)(bn + row) * K + k0 + part * 8;
            } else {
                if (tile == 0)      g = Ah + (size_t)(bm + row) * K + k0 + part * 8;
                else if (tile == 1) g = Bh + (size_t)(bn + row) * K + k0 + part * 8;
                else                g = Bl + (size_t)(bn + row) * K + k0 + part * 8;
            }
            __builtin_amdgcn_global_load_lds(
                (gvoid_t*)g,
                (svoid_t*)((char*)lds + (size_t)c * 16),
                16, 0, 0);
        }
        __syncthreads();

        bf16x8 ah[4], al[4], bh[4], bl[4];
#pragma unroll
        for (int mi = 0; mi < 4; mi++) {
            int r = wm * 64 + mi * 16 + lrow;
            ah[mi] = *(const bf16x8*)&Ahs[r * 32 + quad * 8];
            if (ASPLIT) al[mi] = *(const bf16x8*)&Als[r * 32 + quad * 8];
        }
#pragma unroll
        for (int ni = 0; ni < 4; ni++) {
            int r = wn * 64 + ni * 16 + lrow;
            bh[ni] = *(const bf16x8*)&Bhs[r * 32 + quad * 8];
            bl[ni] = *(const bf16x8*)&Bls[r * 32 + quad * 8];
        }
#pragma unroll
        for (int mi = 0; mi < 4; mi++)
#pragma unroll
            for (int ni = 0; ni < 4; ni++) {
                acc[mi][ni] = __builtin_amdgcn_mfma_f32_16x16x32_bf16(ah[mi], bh[ni], acc[mi][ni], 0, 0, 0);
                acc[mi][ni] = __builtin_amdgcn_mfma_f32_16x16x32_bf16(ah[mi], bl[ni], acc[mi][ni], 0, 0, 0);
                if (ASPLIT)
                    acc[mi][ni] = __builtin_amdgcn_mfma_f32_16x16x32_bf16(al[mi], bh[ni], acc[mi][ni], 0, 0, 0);
            }
        __syncthreads();
    }

    float bv[4];
#pragma unroll
    for (int ni = 0; ni < 4; ni++) bv[ni] = bias[bn + wn * 64 + ni * 16 + lrow];
#pragma unroll
    for (int mi = 0; mi < 4; mi++) {
        int row0 = bm + wm * 64 + mi * 16 + quad * 4;
        float dsc[4];
        if (SCALEOUT) {
#pragma unroll
            for (int r = 0; r < 4; r++)
                dsc[r] = (row0 + r < N_NODES) ? dscale[row0 + r] : 0.f;
        }
#pragma unroll
        for (int ni = 0; ni < 4; ni++) {
            int col = bn + wn * 64 + ni * 16 + lrow;
#pragma unroll
            for (int r = 0; r < 4; r++) {
                int row = row0 + r;
                if (row < N_NODES) {
                    float v = fmaxf(acc[mi][ni][r] + bv[ni], 0.f);
                    if (SCALEOUT) v *= dsc[r];
                    Cout[(size_t)row * 256 + col] = f2bf(v);
                }
            }
        }
    }
}

// ---------------- fused mean-pool (batch sorted, h in bf16) + MLP head ----------
__global__ __launch_bounds__(256) void pool_mlp_kernel(const unsigned short* __restrict__ h,
                                                       const int* __restrict__ batch,
                                                       const float* __restrict__ Wf1,
                                                       const float* __restrict__ bf1,
                                                       const float* __restrict__ Wf2,
                                                       const float* __restrict__ bf2,
                                                       float* __restrict__ out) {
    int g = blockIdx.x;
    int t = threadIdx.x;  // 0..255
    __shared__ int bounds[2];
    if (t < 2) {
        int target = g + t;
        int lo = 0, hi = N_NODES;
        while (lo < hi) {
            int mid = (lo + hi) >> 1;
            if (batch[mid] < target) lo = mid + 1;
            else hi = mid;
        }
        bounds[t] = lo;
    }
    __syncthreads();
    int lo = bounds[0], hi = bounds[1];

    float a0 = 0.f, a1 = 0.f, a2 = 0.f, a3 = 0.f;
    int n = lo;
    for (; n + 4 <= hi; n += 4) {
        unsigned short v0 = h[(size_t)n * HID + t];
        unsigned short v1 = h[(size_t)(n + 1) * HID + t];
        unsigned short v2 = h[(size_t)(n + 2) * HID + t];
        unsigned short v3 = h[(size_t)(n + 3) * HID + t];
        a0 += bf2f(v0); a1 += bf2f(v1); a2 += bf2f(v2); a3 += bf2f(v3);
    }
    for (; n < hi; n++) a0 += bf2f(h[(size_t)n * HID + t]);
    float acc = (a0 + a1) + (a2 + a3);
    float inv = (hi > lo) ? 1.0f / (float)(hi - lo) : 0.f;
    __shared__ float p[256];
    p[t] = acc * inv;
    __syncthreads();

    float hv = 0.f;
    if (t < 128) {
        float a = bf1[t];
#pragma unroll 8
        for (int k = 0; k < 256; k++) a = fmaf(p[k], Wf1[k * 128 + t], a);
        hv = fmaxf(a, 0.f) * Wf2[t];
    }
#pragma unroll
    for (int off = 32; off > 0; off >>= 1) hv += __shfl_down(hv, off, 64);
    __shared__ float partial[4];
    if ((t & 63) == 0) partial[t >> 6] = hv;
    __syncthreads();
    if (t == 0) out[g] = partial[0] + partial[1] + bf2[0];
}

extern "C" void kernel_launch(void* const* d_in, const int* in_sizes, int n_in,
                              void* d_out, int out_size, void* d_ws, size_t ws_size,
                              hipStream_t stream) {
    const float* x   = (const float*)d_in[0];
    const int*   ei  = (const int*)d_in[1];
    const int*   bat = (const int*)d_in[2];
    const float* W1  = (const float*)d_in[3];
    const float* b1  = (const float*)d_in[4];
    const float* W2  = (const float*)d_in[5];
    const float* b2  = (const float*)d_in[6];
    const float* Wf1 = (const float*)d_in[7];
    const float* bf1 = (const float*)d_in[8];
    const float* Wf2 = (const float*)d_in[9];
    const float* bf2 = (const float*)d_in[10];
    float* out = (float*)d_out;

    char* ws = (char*)d_ws;
    // layout (peak end 0x9B20000 = 162.5 MB):
    //   0x0000000 deg        0x0080000 dinv      0x0100000 rowptr
    //   0x01F0000 bsum
    //   0x0200000 esrc (6.4 MB)
    //   0x0820000 W1th  0x0830000 W1tl  0x0840000 W2th  0x0860000 W2tl
    //   0x0880000 A1h (25.6 MB) / later A2 (51.2 MB, single)
    //   0x20F0000 eord (6.4 MB, dead after fill) -> A1l (25.6 MB)  [A2 overlaps]
    //   0x6A40000 xbf (25.6 MB) -> H1bf (51.2 MB) -> H2bf (51.2 MB) time-multiplexed
    int*   deg    = (int*)(ws);
    float* dinv   = (float*)(ws + 0x0080000);
    int*   rowptr = (int*)(ws + 0x0100000);
    int*   bsum   = (int*)(ws + 0x01F0000);
    int*   esrc   = (int*)(ws + 0x0200000);
    unsigned short* W1th = (unsigned short*)(ws + 0x0820000);
    unsigned short* W1tl = (unsigned short*)(ws + 0x0830000);
    unsigned short* W2th = (unsigned short*)(ws + 0x0840000);
    unsigned short* W2tl = (unsigned short*)(ws + 0x0860000);
    unsigned short* A1h  = (unsigned short*)(ws + 0x0880000);
    int*   eord   = (int*)(ws + 0x20F0000);                    // dead before A1l written
    unsigned short* A1l  = (unsigned short*)(ws + 0x20F0000);
    unsigned short* A2   = (unsigned short*)(ws + 0x0880000);  // reuses A1h+A1l space
    unsigned short* xbf  = (unsigned short*)(ws + 0x6A40000);
    unsigned short* H1bf = (unsigned short*)(ws + 0x6A40000);  // overwrites dead xbf
    unsigned short* H2bf = (unsigned short*)(ws + 0x6A40000);  // overwrites dead H1bf
    (void)ws_size;

    hipMemsetAsync(deg, 0, (size_t)N_NODES * sizeof(int), stream);

    // CSR build front half (produces dinv needed by the prescaled prep)
    count_deg_kernel<<<(N_EDGES + 255) / 256, 256, 0, stream>>>(ei, deg, eord);
    blocksum_kernel<<<SCAN_BLOCKS, 1024, 0, stream>>>(deg, bsum, dinv);

    // merged prep (x prescale+cast, weight transpose+split)
    prep_kernel<<<X2BF_BLOCKS + 384, 256, 0, stream>>>(x, dinv, xbf, W1, W2,
                                                       W1th, W1tl, W2th, W2tl);

    // CSR build back half (scanout now inlines the 98-value block-sum scan)
    scanout_kernel<<<SCAN_BLOCKS, 1024, 0, stream>>>(deg, bsum, rowptr);
    fill_kernel<<<(N_EDGES + 255) / 256, 256, 0, stream>>>(ei, rowptr, eord, esrc);

    // layer 1: A1 = split(ddst * sum X'); H1' = dinv * relu(A1 @ W1 + b1)  [3-term]
    agg128_kernel<<<N_NODES / 4, 256, 0, stream>>>(xbf, esrc, rowptr, dinv, A1h, A1l);
    {
        dim3 grid(16, 98);
        mfma_gemm_bias_relu<IN_DIM, true, true><<<grid, 256, 0, stream>>>(A1h, A1l, W1th, W1tl, b1, dinv, H1bf);
    }

    // layer 2: A2 = bf16(ddst * sum H1'); H2 = relu(A2 @ W2 + b2)  [2-term]
    agg256_kernel<<<N_NODES / 4, 256, 0, stream>>>(H1bf, esrc, rowptr, dinv, A2);
    {
        dim3 grid(16, 98);
        mfma_gemm_bias_relu<HID, false, false><<<grid, 256, 0, stream>>>(A2, nullptr, W2th, W2tl, b2, nullptr, H2bf);
    }

    // pooling + MLP head (bf16 h)
    pool_mlp_kernel<<<NUM_GRAPHS, 256, 0, stream>>>(H2bf, bat, Wf1, bf1, Wf2, bf2, out);
}

// Round 10
// 510.852 us; speedup vs baseline: 1.0802x; 1.0314x over previous
//
#include <hip/hip_runtime.h>
#include <hip/hip_bf16.h>

#define N_NODES 100000
#define N_EDGES 1600000
#define IN_DIM 128
#define HID 256
#define NUM_GRAPHS 2048
#define M_PAD 100096  // 782 * 128
#define SCAN_BLOCKS 98  // ceil(100000/1024)
#define X2BF_BLOCKS 12500  // N_NODES*IN_DIM/4/256
#define FILL_BLOCKS 784
#define FILL_STRIDE (FILL_BLOCKS * 256)   // 200704
#define FILL_EPT 8                        // edges per thread (784*256*8 >= 1.6M)
#define FILL_PASSES 25                    // buckets of 4096 dst nodes (99999>>12 = 24)

typedef __bf16 bf16x8 __attribute__((ext_vector_type(8)));
typedef float f32x4 __attribute__((ext_vector_type(4)));

typedef const void __attribute__((address_space(1))) gvoid_t;
typedef void __attribute__((address_space(3))) svoid_t;

__device__ inline unsigned short f2bf(float x) {
    union { __hip_bfloat16 h; unsigned short u; } v;
    v.h = __float2bfloat16(x);
    return v.u;
}
__device__ inline float bf2f(unsigned short u) {
    return __uint_as_float(((unsigned int)u) << 16);
}
__device__ inline int rfl(int x) { return __builtin_amdgcn_readfirstlane(x); }

// ---------------- degree histogram over dst + per-edge ordinal ----------------
__global__ void count_deg_kernel(const int* __restrict__ ei, int* __restrict__ deg,
                                 int* __restrict__ eord) {
    int e = blockIdx.x * blockDim.x + threadIdx.x;
    if (e < N_EDGES) {
        eord[e] = atomicAdd(&deg[ei[N_EDGES + e]], 1);
    }
}

// ---------------- block sums (+ fused dinv) ----------------
__global__ __launch_bounds__(1024) void blocksum_kernel(const int* __restrict__ deg,
                                                        int* __restrict__ bsum,
                                                        float* __restrict__ dinv) {
    int i = blockIdx.x * 1024 + threadIdx.x;
    int v = (i < N_NODES) ? deg[i] : 0;
    if (i < N_NODES) dinv[i] = rsqrtf((float)(v + 1));  // self-loop adds 1
    __shared__ int s[1024];
    int t = threadIdx.x;
    s[t] = v;
    __syncthreads();
#pragma unroll
    for (int off = 512; off > 0; off >>= 1) {
        if (t < off) s[t] += s[t + off];
        __syncthreads();
    }
    if (t == 0) bsum[blockIdx.x] = s[0];
}

// ---------------- scanout with inlined block-sum scan -----------------------
__global__ __launch_bounds__(1024) void scanout_kernel(const int* __restrict__ deg,
                                                       const int* __restrict__ bsum,
                                                       int* __restrict__ rowptr) {
    int t = threadIdx.x;
    __shared__ int bs[128];
    if (t < 128) bs[t] = (t < SCAN_BLOCKS) ? bsum[t] : 0;
    __syncthreads();
#pragma unroll
    for (int off = 1; off < 128; off <<= 1) {
        int x = 0;
        if (t < 128 && t >= off) x = bs[t - off];
        __syncthreads();
        if (t < 128) bs[t] += x;
        __syncthreads();
    }
    int base = (blockIdx.x > 0) ? bs[blockIdx.x - 1] : 0;

    int i = blockIdx.x * 1024 + t;
    int v = (i < N_NODES) ? deg[i] : 0;
    __shared__ int s[1024];
    s[t] = v;
    __syncthreads();
#pragma unroll
    for (int off = 1; off < 1024; off <<= 1) {
        int x = (t >= off) ? s[t - off] : 0;
        __syncthreads();
        s[t] += x;
        __syncthreads();
    }
    int excl = (t > 0) ? s[t - 1] : 0;
    if (i < N_NODES) rowptr[i] = base + excl;
    if (i == N_NODES - 1) rowptr[N_NODES] = base + s[t];
}

// ---------------- bucket fill: register-resident multi-pass ----------------
// Each thread loads its 8 edges (src, final position) ONCE into registers,
// then 25 passes over dst-buckets of 4096 nodes: pass p writes only edges in
// bucket p. Active esrc window per pass <= 4096*avgdeg*4B ~= 256 KB -> partial
// 64B lines stay L2-resident between the ~16 scattered writes they receive
// (instead of round-tripping HBM: r3 measured 107 MB WRITE for 6.4 MB logical).
// All 784 blocks are co-resident (~3/CU) so pass phases align chip-wide.
__global__ __launch_bounds__(256) void fill_kernel(const int* __restrict__ ei,
                                                   const int* __restrict__ rowptr,
                                                   const int* __restrict__ eord,
                                                   int* __restrict__ esrc) {
    int base = blockIdx.x * 256 + threadIdx.x;
    int src[FILL_EPT], pos[FILL_EPT], bkt[FILL_EPT];
#pragma unroll
    for (int i = 0; i < FILL_EPT; i++) {
        int e = base + i * FILL_STRIDE;
        if (e < N_EDGES) {
            int d = ei[N_EDGES + e];
            src[i] = ei[e];
            pos[i] = rowptr[d] + eord[e];
            bkt[i] = d >> 12;
        } else {
            bkt[i] = -1;
        }
    }
    for (int p = 0; p < FILL_PASSES; p++) {
#pragma unroll
        for (int i = 0; i < FILL_EPT; i++) {
            if (bkt[i] == p) esrc[pos[i]] = src[i];
        }
    }
}

// ---------------- merged prep: x->bf16 prescaled  +  weight transpose/split ----
__global__ void prep_kernel(const float* __restrict__ x, const float* __restrict__ dinv,
                            unsigned short* __restrict__ xb,
                            const float* __restrict__ W1, const float* __restrict__ W2,
                            unsigned short* __restrict__ W1th, unsigned short* __restrict__ W1tl,
                            unsigned short* __restrict__ W2th, unsigned short* __restrict__ W2tl) {
    int b = blockIdx.x;
    if (b < X2BF_BLOCKS) {
        size_t i = ((size_t)b * 256 + threadIdx.x) * 4;
        int node = (int)(i >> 7);  // 128 floats per row
        float dv = dinv[node];
        float4 v = *(const float4*)(x + i);
        ushort4 o;
        o.x = f2bf(v.x * dv); o.y = f2bf(v.y * dv);
        o.z = f2bf(v.z * dv); o.w = f2bf(v.w * dv);
        *(ushort4*)(xb + i) = o;
    } else {
        int idx = (b - X2BF_BLOCKS) * 256 + threadIdx.x;
        if (idx < IN_DIM * 256) {
            int k = idx >> 8, n = idx & 255;
            float w = W1[idx];
            unsigned short h = f2bf(w);
            unsigned short l = f2bf(w - bf2f(h));
            W1th[n * IN_DIM + k] = h;
            W1tl[n * IN_DIM + k] = l;
        } else {
            int i2 = idx - IN_DIM * 256;
            int k = i2 >> 8, n = i2 & 255;
            float w = W2[i2];
            unsigned short h = f2bf(w);
            unsigned short l = f2bf(w - bf2f(h));
            W2th[n * HID + k] = h;
            W2tl[n * HID + k] = l;
        }
    }
}

// ---------------- gather agg 128-dim from prescaled bf16, hi/lo out ----------
__global__ __launch_bounds__(256) void agg128_kernel(const unsigned short* __restrict__ X,
                                                     const int* __restrict__ esrc,
                                                     const int* __restrict__ rowptr,
                                                     const float* __restrict__ dinv,
                                                     unsigned short* __restrict__ Ah,
                                                     unsigned short* __restrict__ Al) {
    int node = rfl(blockIdx.x * 4 + (threadIdx.x >> 6));
    int lane = threadIdx.x & 63;
    float ddst = dinv[node];
    int s = rfl(rowptr[node]);
    int e = rfl(rowptr[node + 1]);

    ushort2 h0 = *((const ushort2*)(X + (size_t)node * 128) + lane);
    float2 acc = make_float2(bf2f(h0.x), bf2f(h0.y));

    int j = s;
    for (; j + 8 <= e; j += 8) {
        int si[8];
#pragma unroll
        for (int u = 0; u < 8; u++) si[u] = rfl(esrc[j + u]);
        ushort2 xv[8];
#pragma unroll
        for (int u = 0; u < 8; u++)
            xv[u] = *((const ushort2*)(X + (size_t)si[u] * 128) + lane);
#pragma unroll
        for (int u = 0; u < 8; u++) {
            acc.x += bf2f(xv[u].x);
            acc.y += bf2f(xv[u].y);
        }
    }
    for (; j + 4 <= e; j += 4) {
        int si[4];
#pragma unroll
        for (int u = 0; u < 4; u++) si[u] = rfl(esrc[j + u]);
        ushort2 xv[4];
#pragma unroll
        for (int u = 0; u < 4; u++)
            xv[u] = *((const ushort2*)(X + (size_t)si[u] * 128) + lane);
#pragma unroll
        for (int u = 0; u < 4; u++) {
            acc.x += bf2f(xv[u].x);
            acc.y += bf2f(xv[u].y);
        }
    }
    for (; j < e; j++) {
        int src = rfl(esrc[j]);
        ushort2 xv = *((const ushort2*)(X + (size_t)src * 128) + lane);
        acc.x += bf2f(xv.x);
        acc.y += bf2f(xv.y);
    }
    acc.x *= ddst;
    acc.y *= ddst;
    size_t o = (size_t)node * 128 + lane * 2;
    ushort2 hi, lo;
    hi.x = f2bf(acc.x); lo.x = f2bf(acc.x - bf2f(hi.x));
    hi.y = f2bf(acc.y); lo.y = f2bf(acc.y - bf2f(hi.y));
    *(ushort2*)(Ah + o) = hi;
    *(ushort2*)(Al + o) = lo;
}

// ---------------- gather agg 256-dim from prescaled bf16, hi out ----------
__global__ __launch_bounds__(256) void agg256_kernel(const unsigned short* __restrict__ H,
                                                     const int* __restrict__ esrc,
                                                     const int* __restrict__ rowptr,
                                                     const float* __restrict__ dinv,
                                                     unsigned short* __restrict__ Ah) {
    int node = rfl(blockIdx.x * 4 + (threadIdx.x >> 6));
    int lane = threadIdx.x & 63;
    float ddst = dinv[node];
    int s = rfl(rowptr[node]);
    int e = rfl(rowptr[node + 1]);

    ushort4 h0 = *((const ushort4*)(H + (size_t)node * 256) + lane);
    float4 acc = make_float4(bf2f(h0.x), bf2f(h0.y), bf2f(h0.z), bf2f(h0.w));

    int j = s;
    for (; j + 8 <= e; j += 8) {
        int si[8];
#pragma unroll
        for (int u = 0; u < 8; u++) si[u] = rfl(esrc[j + u]);
        ushort4 xv[8];
#pragma unroll
        for (int u = 0; u < 8; u++)
            xv[u] = *((const ushort4*)(H + (size_t)si[u] * 256) + lane);
#pragma unroll
        for (int u = 0; u < 8; u++) {
            acc.x += bf2f(xv[u].x);
            acc.y += bf2f(xv[u].y);
            acc.z += bf2f(xv[u].z);
            acc.w += bf2f(xv[u].w);
        }
    }
    for (; j + 4 <= e; j += 4) {
        int si[4];
#pragma unroll
        for (int u = 0; u < 4; u++) si[u] = rfl(esrc[j + u]);
        ushort4 xv[4];
#pragma unroll
        for (int u = 0; u < 4; u++)
            xv[u] = *((const ushort4*)(H + (size_t)si[u] * 256) + lane);
#pragma unroll
        for (int u = 0; u < 4; u++) {
            acc.x += bf2f(xv[u].x);
            acc.y += bf2f(xv[u].y);
            acc.z += bf2f(xv[u].z);
            acc.w += bf2f(xv[u].w);
        }
    }
    for (; j < e; j++) {
        int src = rfl(esrc[j]);
        ushort4 xv = *((const ushort4*)(H + (size_t)src * 256) + lane);
        acc.x += bf2f(xv.x);
        acc.y += bf2f(xv.y);
        acc.z += bf2f(xv.z);
        acc.w += bf2f(xv.w);
    }
    acc.x *= ddst; acc.y *= ddst; acc.z *= ddst; acc.w *= ddst;
    size_t o = (size_t)node * 256 + lane * 4;
    ushort4 hi;
    hi.x = f2bf(acc.x); hi.y = f2bf(acc.y);
    hi.z = f2bf(acc.z); hi.w = f2bf(acc.w);
    *(ushort4*)(Ah + o) = hi;
}

// ---------------- MFMA GEMM: C = relu(A @ W + b) [optionally * dinv[row]] ------
template <int K, bool ASPLIT, bool SCALEOUT>
__launch_bounds__(256, 2)
__global__ void mfma_gemm_bias_relu(const unsigned short* __restrict__ Ah,
                                    const unsigned short* __restrict__ Al,
                                    const unsigned short* __restrict__ Bh,
                                    const unsigned short* __restrict__ Bl,
                                    const float* __restrict__ bias,
                                    const float* __restrict__ dscale,
                                    unsigned short* __restrict__ Cout) {
    constexpr int NT = ASPLIT ? 4 : 3;
    __shared__ __align__(16) unsigned short lds[NT * 128 * 32];
    unsigned short* Ahs = lds;
    unsigned short* Als = lds + 4096;                    // only valid if ASPLIT
    unsigned short* Bhs = lds + (ASPLIT ? 8192 : 4096);
    unsigned short* Bls = lds + (ASPLIT ? 12288 : 8192);

    int tid = threadIdx.x;
    int bm = (blockIdx.y * 8 + (blockIdx.x & 7)) * 128;
    int bn = (blockIdx.x >> 3) * 128;
    int wid = tid >> 6, lane = tid & 63;
    int wm = wid & 1, wn = wid >> 1;
    int lrow = lane & 15, quad = lane >> 4;

    f32x4 acc[4][4];
#pragma unroll
    for (int mi = 0; mi < 4; mi++)
#pragma unroll
        for (int ni = 0; ni < 4; ni++) acc[mi][ni] = (f32x4){0.f, 0.f, 0.f, 0.f};

    for (int k0 = 0; k0 < K; k0 += 32) {
#pragma unroll
        for (int i = 0; i < NT * 2; i++) {
            int c = tid + 256 * i;
            int tile = c >> 9;
            int w = c & 511;
            int row = w >> 2;
            int part = w & 3;
            const unsigned short* g;
            if (ASPLIT) {
                if (tile == 0)      g = Ah + (size_t)(bm + row) * K + k0 + part * 8;
                else if (tile == 1) g = Al + (size_t)(bm + row) * K + k0 + part * 8;
                else if (tile == 2) g = Bh + (size_t)(bn + row) * K + k0 + part * 8;
                else                g = Bl + (size_t)(bn + row) * K + k0 + part * 8;
            } else {
                if (tile == 0)      g = Ah + (size_t)(bm + row) * K + k0 + part * 8;
                else if (tile == 1) g = Bh + (size_t)(bn + row) * K + k0 + part * 8;
                else                g = Bl + (size_t)(bn + row) * K + k0 + part * 8;
            }
            __builtin_amdgcn_global_load_lds(
                (gvoid_t*)g,
                (svoid_t*)((char*)lds + (size_t)c * 16),
                16, 0, 0);
        }
        __syncthreads();

        bf16x8 ah[4], al[4], bh[4], bl[4];
#pragma unroll
        for (int mi = 0; mi < 4; mi++) {
            int r = wm * 64 + mi * 16 + lrow;
            ah[mi] = *(const bf16x8*)&Ahs[r * 32 + quad * 8];
            if (ASPLIT) al[mi] = *(const bf16x8*)&Als[r * 32 + quad * 8];
        }
#pragma unroll
        for (int ni = 0; ni < 4; ni++) {
            int r = wn * 64 + ni * 16 + lrow;
            bh[ni] = *(const bf16x8*)&Bhs[r * 32 + quad * 8];
            bl[ni] = *(const bf16x8*)&Bls[r * 32 + quad * 8];
        }
#pragma unroll
        for (int mi = 0; mi < 4; mi++)
#pragma unroll
            for (int ni = 0; ni < 4; ni++) {
                acc[mi][ni] = __builtin_amdgcn_mfma_f32_16x16x32_bf16(ah[mi], bh[ni], acc[mi][ni], 0, 0, 0);
                acc[mi][ni] = __builtin_amdgcn_mfma_f32_16x16x32_bf16(ah[mi], bl[ni], acc[mi][ni], 0, 0, 0);
                if (ASPLIT)
                    acc[mi][ni] = __builtin_amdgcn_mfma_f32_16x16x32_bf16(al[mi], bh[ni], acc[mi][ni], 0, 0, 0);
            }
        __syncthreads();
    }

    float bv[4];
#pragma unroll
    for (int ni = 0; ni < 4; ni++) bv[ni] = bias[bn + wn * 64 + ni * 16 + lrow];
#pragma unroll
    for (int mi = 0; mi < 4; mi++) {
        int row0 = bm + wm * 64 + mi * 16 + quad * 4;
        float dsc[4];
        if (SCALEOUT) {
#pragma unroll
            for (int r = 0; r < 4; r++)
                dsc[r] = (row0 + r < N_NODES) ? dscale[row0 + r] : 0.f;
        }
#pragma unroll
        for (int ni = 0; ni < 4; ni++) {
            int col = bn + wn * 64 + ni * 16 + lrow;
#pragma unroll
            for (int r = 0; r < 4; r++) {
                int row = row0 + r;
                if (row < N_NODES) {
                    float v = fmaxf(acc[mi][ni][r] + bv[ni], 0.f);
                    if (SCALEOUT) v *= dsc[r];
                    Cout[(size_t)row * 256 + col] = f2bf(v);
                }
            }
        }
    }
}

// ---------------- fused mean-pool (batch sorted, h in bf16) + MLP head ----------
// Wave w handles rows lo+w, lo+w+4, ...; lane l loads ushort4 (8 B, G13) for
// cols 4l..4l+3 -> one wave reads a full 512 B row per instruction, 4 rows in
// flight per block. Cross-wave reduce via 4 KB LDS tile.
__global__ __launch_bounds__(256) void pool_mlp_kernel(const unsigned short* __restrict__ h,
                                                       const int* __restrict__ batch,
                                                       const float* __restrict__ Wf1,
                                                       const float* __restrict__ bf1,
                                                       const float* __restrict__ Wf2,
                                                       const float* __restrict__ bf2,
                                                       float* __restrict__ out) {
    int g = blockIdx.x;
    int t = threadIdx.x;  // 0..255
    int w = t >> 6, l = t & 63;
    __shared__ int bounds[2];
    if (t < 2) {
        int target = g + t;
        int lo = 0, hi = N_NODES;
        while (lo < hi) {
            int mid = (lo + hi) >> 1;
            if (batch[mid] < target) lo = mid + 1;
            else hi = mid;
        }
        bounds[t] = lo;
    }
    __syncthreads();
    int lo = bounds[0], hi = bounds[1];

    float4 a4 = make_float4(0.f, 0.f, 0.f, 0.f);
    for (int n = lo + w; n < hi; n += 4) {
        ushort4 v = *((const ushort4*)(h + (size_t)n * HID) + l);
        a4.x += bf2f(v.x); a4.y += bf2f(v.y);
        a4.z += bf2f(v.z); a4.w += bf2f(v.w);
    }
    __shared__ float ps[4][256];
    *(float4*)&ps[w][l * 4] = a4;
    __syncthreads();

    float inv = (hi > lo) ? 1.0f / (float)(hi - lo) : 0.f;
    __shared__ float p[256];
    p[t] = (ps[0][t] + ps[1][t] + ps[2][t] + ps[3][t]) * inv;
    __syncthreads();

    float hv = 0.f;
    if (t < 128) {
        float a = bf1[t];
#pragma unroll 8
        for (int k = 0; k < 256; k++) a = fmaf(p[k], Wf1[k * 128 + t], a);
        hv = fmaxf(a, 0.f) * Wf2[t];
    }
#pragma unroll
    for (int off = 32; off > 0; off >>= 1) hv += __shfl_down(hv, off, 64);
    __shared__ float partial[4];
    if ((t & 63) == 0) partial[t >> 6] = hv;
    __syncthreads();
    if (t == 0) out[g] = partial[0] + partial[1] + bf2[0];
}

extern "C" void kernel_launch(void* const* d_in, const int* in_sizes, int n_in,
                              void* d_out, int out_size, void* d_ws, size_t ws_size,
                              hipStream_t stream) {
    const float* x   = (const float*)d_in[0];
    const int*   ei  = (const int*)d_in[1];
    const int*   bat = (const int*)d_in[2];
    const float* W1  = (const float*)d_in[3];
    const float* b1  = (const float*)d_in[4];
    const float* W2  = (const float*)d_in[5];
    const float* b2  = (const float*)d_in[6];
    const float* Wf1 = (const float*)d_in[7];
    const float* bf1 = (const float*)d_in[8];
    const float* Wf2 = (const float*)d_in[9];
    const float* bf2 = (const float*)d_in[10];
    float* out = (float*)d_out;

    char* ws = (char*)d_ws;
    // layout (peak end 0x9B20000 = 162.5 MB):
    //   0x0000000 deg        0x0080000 dinv      0x0100000 rowptr
    //   0x01F0000 bsum
    //   0x0200000 esrc (6.4 MB)
    //   0x0820000 W1th  0x0830000 W1tl  0x0840000 W2th  0x0860000 W2tl
    //   0x0880000 A1h (25.6 MB) / later A2 (51.2 MB, single)
    //   0x20F0000 eord (6.4 MB, dead after fill) -> A1l (25.6 MB)  [A2 overlaps]
    //   0x6A40000 xbf (25.6 MB) -> H1bf (51.2 MB) -> H2bf (51.2 MB) time-multiplexed
    int*   deg    = (int*)(ws);
    float* dinv   = (float*)(ws + 0x0080000);
    int*   rowptr = (int*)(ws + 0x0100000);
    int*   bsum   = (int*)(ws + 0x01F0000);
    int*   esrc   = (int*)(ws + 0x0200000);
    unsigned short* W1th = (unsigned short*)(ws + 0x0820000);
    unsigned short* W1tl = (unsigned short*)(ws + 0x0830000);
    unsigned short* W2th = (unsigned short*)(ws + 0x0840000);
    unsigned short* W2tl = (unsigned short*)(ws + 0x0860000);
    unsigned short* A1h  = (unsigned short*)(ws + 0x0880000);
    int*   eord   = (int*)(ws + 0x20F0000);                    // dead before A1l written
    unsigned short* A1l  = (unsigned short*)(ws + 0x20F0000);
    unsigned short* A2   = (unsigned short*)(ws + 0x0880000);  // reuses A1h+A1l space
    unsigned short* xbf  = (unsigned short*)(ws + 0x6A40000);
    unsigned short* H1bf = (unsigned short*)(ws + 0x6A40000);  // overwrites dead xbf
    unsigned short* H2bf = (unsigned short*)(ws + 0x6A40000);  // overwrites dead H1bf
    (void)ws_size;

    hipMemsetAsync(deg, 0, (size_t)N_NODES * sizeof(int), stream);

    // CSR build front half (produces dinv needed by the prescaled prep)
    count_deg_kernel<<<(N_EDGES + 255) / 256, 256, 0, stream>>>(ei, deg, eord);
    blocksum_kernel<<<SCAN_BLOCKS, 1024, 0, stream>>>(deg, bsum, dinv);

    // merged prep (x prescale+cast, weight transpose+split)
    prep_kernel<<<X2BF_BLOCKS + 384, 256, 0, stream>>>(x, dinv, xbf, W1, W2,
                                                       W1th, W1tl, W2th, W2tl);

    // CSR build back half
    scanout_kernel<<<SCAN_BLOCKS, 1024, 0, stream>>>(deg, bsum, rowptr);
    fill_kernel<<<FILL_BLOCKS, 256, 0, stream>>>(ei, rowptr, eord, esrc);

    // layer 1: A1 = split(ddst * sum X'); H1' = dinv * relu(A1 @ W1 + b1)  [3-term]
    agg128_kernel<<<N_NODES / 4, 256, 0, stream>>>(xbf, esrc, rowptr, dinv, A1h, A1l);
    {
        dim3 grid(16, 98);
        mfma_gemm_bias_relu<IN_DIM, true, true><<<grid, 256, 0, stream>>>(A1h, A1l, W1th, W1tl, b1, dinv, H1bf);
    }

    // layer 2: A2 = bf16(ddst * sum H1'); H2 = relu(A2 @ W2 + b2)  [2-term]
    agg256_kernel<<<N_NODES / 4, 256, 0, stream>>>(H1bf, esrc, rowptr, dinv, A2);
    {
        dim3 grid(16, 98);
        mfma_gemm_bias_relu<HID, false, false><<<grid, 256, 0, stream>>>(A2, nullptr, W2th, W2tl, b2, nullptr, H2bf);
    }

    // pooling + MLP head (bf16 h)
    pool_mlp_kernel<<<NUM_GRAPHS, 256, 0, stream>>>(H2bf, bat, Wf1, bf1, Wf2, bf2, out);
}